// Round 4
// baseline (1430.711 us; speedup 1.0000x reference)
//
#include <hip/hip_runtime.h>
#include <hip/hip_bf16.h>
#include <math.h>

typedef __bf16 bf16;
typedef bf16 bf16x4 __attribute__((ext_vector_type(4)));
typedef bf16 bf16x8 __attribute__((ext_vector_type(8)));
typedef float f32x4 __attribute__((ext_vector_type(4)));

#define B_ 4
#define S_ 2048
#define HID_ 1024
#define NH_ 16
#define HD_ 64

// async global->LDS, 16B per lane. LDS dest must be wave-uniform base + lane*16.
__device__ __forceinline__ void async16(const bf16* g, bf16* l) {
  __builtin_amdgcn_global_load_lds(
      (const __attribute__((address_space(1))) void*)g,
      (__attribute__((address_space(3))) void*)l, 16, 0, 0);
}

// ---------------- fp32 -> bf16 convert (vector: 4 floats -> 4 bf16 per thread)
__global__ void cvt_kernel(const float* __restrict__ src, bf16* __restrict__ dst, int n4) {
  int i = blockIdx.x * 256 + threadIdx.x;
  if (i < n4) {
    float4 v = ((const float4*)src)[i];
    bf16x4 o;
    o[0] = (bf16)v.x; o[1] = (bf16)v.y; o[2] = (bf16)v.z; o[3] = (bf16)v.w;
    ((bf16x4*)dst)[i] = o;
  }
}

// ---------------- QKV GEMM: Y = Xb @ Wb^T  (M=8192, N=1024, K=1024), fused inline RoPE.
// z=0 -> Q (scaled 1/8, RoPE) [B,H,S,D]; z=1 -> K (RoPE) [B,H,S,D]; z=2 -> V^T [B,H,D,S]
__global__ __launch_bounds__(256, 2) void qkv_gemm(
    const bf16* __restrict__ X, const bf16* __restrict__ Wq,
    const bf16* __restrict__ Wk, const bf16* __restrict__ Wv,
    const int* __restrict__ pos,
    bf16* __restrict__ Q, bf16* __restrict__ Ko, bf16* __restrict__ Vt) {
  const int z = blockIdx.z;
  const bf16* W = (z == 0) ? Wq : (z == 1) ? Wk : Wv;
  const int m0 = blockIdx.y * 128;
  const int n0 = blockIdx.x * 128;
  __shared__ __align__(16) bf16 lA[128 * 32];
  __shared__ __align__(16) bf16 lB[128 * 32];
  const int tid = threadIdx.x;
  const int lane = tid & 63, w = tid >> 6;
  const int wm = (w >> 1) * 64, wn = (w & 1) * 64;
  const int quad = lane >> 4, l16 = lane & 15;

  f32x4 acc[4][4] = {};

  const int qa = tid, qb = tid + 256;           // 512 chunks of 8 bf16 per [128][32] tile
  const int ra = qa >> 2, ca = (qa & 3) * 8;
  const int rb = qb >> 2, cb = (qb & 3) * 8;

  for (int k0 = 0; k0 < 1024; k0 += 32) {
    async16(X + (size_t)(m0 + ra) * 1024 + k0 + ca, lA + qa * 8);
    async16(X + (size_t)(m0 + rb) * 1024 + k0 + cb, lA + qb * 8);
    async16(W + (size_t)(n0 + ra) * 1024 + k0 + ca, lB + qa * 8);
    async16(W + (size_t)(n0 + rb) * 1024 + k0 + cb, lB + qb * 8);
    __syncthreads();
    bf16x8 af[4], bfr[4];
#pragma unroll
    for (int i = 0; i < 4; i++)
      af[i] = *(const bf16x8*)(lA + (wm + i * 16 + l16) * 32 + quad * 8);
#pragma unroll
    for (int j = 0; j < 4; j++)
      bfr[j] = *(const bf16x8*)(lB + (wn + j * 16 + l16) * 32 + quad * 8);
#pragma unroll
    for (int i = 0; i < 4; i++)
#pragma unroll
      for (int j = 0; j < 4; j++)
        acc[i][j] = __builtin_amdgcn_mfma_f32_16x16x32_bf16(af[i], bfr[j], acc[i][j], 0, 0, 0);
    __syncthreads();
  }

  // epilogue: C/D layout row m_loc = wm+i*16+quad*4+r, col n_loc = wn+j*16+l16
  const int h = (n0 + wn) >> 6;  // head (64-wide, wave-aligned); d = j*16+l16
  if (z <= 1) {
    bf16* dst = (z == 0) ? Q : Ko;
    const float scl = (z == 0) ? 0.125f : 1.0f;
    const float invf0 = expf(-0.28782313662425572f * (float)l16);         // ln(1e4)/32
    const float invf1 = expf(-0.28782313662425572f * (float)(16 + l16));
#pragma unroll
    for (int i = 0; i < 4; i++)
#pragma unroll
      for (int r = 0; r < 4; r++) {
        int m = m0 + wm + i * 16 + quad * 4 + r;
        int b = m >> 11, s = m & 2047;
        float p = (float)pos[m];
        size_t obase = (((size_t)b * NH_ + h) * S_ + s) * HD_;
#pragma unroll
        for (int j = 0; j < 2; j++) {      // RoPE pair (d, d+32) = frags (j, j+2)
          int d = j * 16 + l16;
          float a = p * (j == 0 ? invf0 : invf1);
          float cv = cosf(a), sv = sinf(a);
          float lo = acc[i][j][r], hi = acc[i][j + 2][r];
          dst[obase + d]      = (bf16)((lo * cv - hi * sv) * scl);
          dst[obase + d + 32] = (bf16)((hi * cv + lo * sv) * scl);
        }
      }
  } else {
#pragma unroll
    for (int i = 0; i < 4; i++)
#pragma unroll
      for (int r = 0; r < 4; r++) {
        int m = m0 + wm + i * 16 + quad * 4 + r;
        int b = m >> 11, s = m & 2047;
#pragma unroll
        for (int j = 0; j < 4; j++) {
          int d = j * 16 + l16;
          Vt[(((size_t)b * NH_ + h) * HD_ + d) * S_ + s] = (bf16)acc[i][j][r];
        }
      }
  }
}

// ---------------- flash attention: block = (64-row Q tile) x (b,h). K/V tiled by 64.
// mask (fp32, zeros here) read directly from global in the softmax step.
__global__ __launch_bounds__(256, 2) void attn_kernel(
    const bf16* __restrict__ Q, const bf16* __restrict__ K,
    const bf16* __restrict__ Vt, const float* __restrict__ mask,
    bf16* __restrict__ ctx) {
  const int b = blockIdx.y >> 4, h = blockIdx.y & 15;
  const int q0 = blockIdx.x * 64;
  __shared__ __align__(16) bf16 lQ[64 * 64];
  __shared__ __align__(16) bf16 lK[64 * 64];
  __shared__ __align__(16) bf16 lV[64 * 64];    // V^T tile: [d][k]
  __shared__ __align__(16) bf16 lP[4][16 * 64]; // per-wave P: [m(16)][k(64)]
  const int tid = threadIdx.x;
  const int lane = tid & 63, w = tid >> 6;
  const int quad = lane >> 4, l16 = lane & 15;

  const size_t headoff = ((size_t)b * NH_ + h) * S_ * HD_;
  {  // stage Q tile once (contiguous 4096 elems)
    const bf16* src = Q + headoff + (size_t)q0 * HD_;
    async16(src + tid * 8, lQ + tid * 8);
    async16(src + (tid + 256) * 8, lQ + (tid + 256) * 8);
  }

  f32x4 oacc[4] = {};
  float m_run[4] = {-1e30f, -1e30f, -1e30f, -1e30f};
  float l_run[4] = {0.f, 0.f, 0.f, 0.f};

  for (int kt = 0; kt < 32; kt++) {
    const int k0 = kt * 64;
    const bf16* ksrc = K + headoff + (size_t)k0 * HD_;  // contiguous tile
    async16(ksrc + tid * 8, lK + tid * 8);
    async16(ksrc + (tid + 256) * 8, lK + (tid + 256) * 8);
    {
      const bf16* vbase = Vt + headoff;                 // [d][s] rows, stride S_
      async16(vbase + (size_t)(tid >> 3) * S_ + k0 + (tid & 7) * 8, lV + tid * 8);
      async16(vbase + (size_t)((tid + 256) >> 3) * S_ + k0 + ((tid + 256) & 7) * 8,
              lV + (tid + 256) * 8);
    }
    __syncthreads();

    // S = (Q/8) K^T : wave w owns S rows w*16..w*16+15, all 64 cols
    f32x4 sacc[4] = {};
#pragma unroll
    for (int ks = 0; ks < 2; ks++) {
      bf16x8 aq = *(const bf16x8*)(lQ + (w * 16 + l16) * 64 + ks * 32 + quad * 8);
#pragma unroll
      for (int j = 0; j < 4; j++) {
        bf16x8 bk = *(const bf16x8*)(lK + (j * 16 + l16) * 64 + ks * 32 + quad * 8);
        sacc[j] = __builtin_amdgcn_mfma_f32_16x16x32_bf16(aq, bk, sacc[j], 0, 0, 0);
      }
    }
    // mask add (fp32 global) + online softmax; quad's 16 lanes hold one row's cols
    float sv[4][4];
#pragma unroll
    for (int r = 0; r < 4; r++) {
      int qrow = q0 + w * 16 + quad * 4 + r;
      const float* mrow = mask + ((size_t)b * S_ + qrow) * S_ + k0;
#pragma unroll
      for (int j = 0; j < 4; j++)
        sv[j][r] = sacc[j][r] + mrow[j * 16 + l16];
    }
#pragma unroll
    for (int r = 0; r < 4; r++) {
      float mx = fmaxf(fmaxf(sv[0][r], sv[1][r]), fmaxf(sv[2][r], sv[3][r]));
      mx = fmaxf(mx, __shfl_xor(mx, 1));   // masks <16 stay within the quad's 16 lanes
      mx = fmaxf(mx, __shfl_xor(mx, 2));
      mx = fmaxf(mx, __shfl_xor(mx, 4));
      mx = fmaxf(mx, __shfl_xor(mx, 8));
      float mnew = fmaxf(m_run[r], mx);
      float alpha = expf(m_run[r] - mnew);
      m_run[r] = mnew;
      float psum = 0.f;
#pragma unroll
      for (int j = 0; j < 4; j++) {
        float p = expf(sv[j][r] - mnew);
        psum += p;
        lP[w][(quad * 4 + r) * 64 + j * 16 + l16] = (bf16)p;  // C/D -> LDS
      }
      psum += __shfl_xor(psum, 1);
      psum += __shfl_xor(psum, 2);
      psum += __shfl_xor(psum, 4);
      psum += __shfl_xor(psum, 8);
      l_run[r] = l_run[r] * alpha + psum;
#pragma unroll
      for (int j = 0; j < 4; j++) oacc[j][r] *= alpha;
    }
    // O += P @ V  (A-layout read of P from LDS; lV rows are d, k-contiguous)
#pragma unroll
    for (int ks = 0; ks < 2; ks++) {
      bf16x8 ap = *(const bf16x8*)(&lP[w][l16 * 64 + ks * 32 + quad * 8]);
#pragma unroll
      for (int j = 0; j < 4; j++) {
        bf16x8 bv = *(const bf16x8*)(lV + (j * 16 + l16) * 64 + ks * 32 + quad * 8);
        oacc[j] = __builtin_amdgcn_mfma_f32_16x16x32_bf16(ap, bv, oacc[j], 0, 0, 0);
      }
    }
    __syncthreads();
  }

  // normalize + store ctx in [B,S,HID] layout so out-proj is a plain GEMM
#pragma unroll
  for (int r = 0; r < 4; r++) {
    float invl = 1.0f / l_run[r];
    int s = q0 + w * 16 + quad * 4 + r;
#pragma unroll
    for (int j = 0; j < 4; j++) {
      int d = j * 16 + l16;
      ctx[((size_t)b * S_ + s) * HID_ + h * HD_ + d] = (bf16)(oacc[j][r] * invl);
    }
  }
}

// ---------------- output projection: out(fp32) = ctx @ Wo^T
__global__ __launch_bounds__(256, 2) void proj_gemm(
    const bf16* __restrict__ A, const bf16* __restrict__ Wo, float* __restrict__ out) {
  const int m0 = blockIdx.y * 128;
  const int n0 = blockIdx.x * 128;
  __shared__ __align__(16) bf16 lA[128 * 32];
  __shared__ __align__(16) bf16 lB[128 * 32];
  const int tid = threadIdx.x;
  const int lane = tid & 63, w = tid >> 6;
  const int wm = (w >> 1) * 64, wn = (w & 1) * 64;
  const int quad = lane >> 4, l16 = lane & 15;

  f32x4 acc[4][4] = {};
  const int qa = tid, qb = tid + 256;
  const int ra = qa >> 2, ca = (qa & 3) * 8;
  const int rb = qb >> 2, cb = (qb & 3) * 8;

  for (int k0 = 0; k0 < 1024; k0 += 32) {
    async16(A + (size_t)(m0 + ra) * 1024 + k0 + ca, lA + qa * 8);
    async16(A + (size_t)(m0 + rb) * 1024 + k0 + cb, lA + qb * 8);
    async16(Wo + (size_t)(n0 + ra) * 1024 + k0 + ca, lB + qa * 8);
    async16(Wo + (size_t)(n0 + rb) * 1024 + k0 + cb, lB + qb * 8);
    __syncthreads();
    bf16x8 af[4], bfr[4];
#pragma unroll
    for (int i = 0; i < 4; i++)
      af[i] = *(const bf16x8*)(lA + (wm + i * 16 + l16) * 32 + quad * 8);
#pragma unroll
    for (int j = 0; j < 4; j++)
      bfr[j] = *(const bf16x8*)(lB + (wn + j * 16 + l16) * 32 + quad * 8);
#pragma unroll
    for (int i = 0; i < 4; i++)
#pragma unroll
      for (int j = 0; j < 4; j++)
        acc[i][j] = __builtin_amdgcn_mfma_f32_16x16x32_bf16(af[i], bfr[j], acc[i][j], 0, 0, 0);
    __syncthreads();
  }
#pragma unroll
  for (int i = 0; i < 4; i++)
#pragma unroll
    for (int r = 0; r < 4; r++) {
      int m = m0 + wm + i * 16 + quad * 4 + r;
#pragma unroll
      for (int j = 0; j < 4; j++)
        out[(size_t)m * 1024 + n0 + wn + j * 16 + l16] = acc[i][j][r];
    }
}

// ---------------- loud-failure sentinel: encodes ws MiB into the output
__global__ void sentinel_kernel(float* out, int n, float val) {
  int i = blockIdx.x * 256 + threadIdx.x;
  if (i < n) out[i] = val;
}

extern "C" void kernel_launch(void* const* d_in, const int* in_sizes, int n_in,
                              void* d_out, int out_size, void* d_ws, size_t ws_size,
                              hipStream_t stream) {
  // Reference dtypes: all tensors fp32, position_ids int32, output fp32.
  const float* X    = (const float*)d_in[0];  // [4,2048,1024]
  const float* mask = (const float*)d_in[1];  // [4,1,2048,2048]
  const int*   pos  = (const int*)d_in[2];    // [4,2048]
  const float* Wq   = (const float*)d_in[3];
  const float* Wk   = (const float*)d_in[4];
  const float* Wv   = (const float*)d_in[5];
  const float* Wo   = (const float*)d_in[6];
  float* out = (float*)d_out;                 // [4,2048,1024] fp32 = 32 MiB

  char* ws = (char*)d_ws;
  const size_t SZ = (size_t)B_ * NH_ * S_ * HD_ * sizeof(bf16);  // 16 MiB
  if (ws_size < 3 * SZ) {  // need 48 MiB; fail loudly with ws MiB encoded
    sentinel_kernel<<<(out_size + 255) / 256, 256, 0, stream>>>(
        out, out_size, (float)(ws_size >> 20));
    return;
  }

  // ws layout (48 MiB): [0,16M) Xb then ctx (overlay, Xb dead after qkv);
  // [16M,32M) Q; [32M,48M) Vt then Wob (overlay, Vt dead after attn).
  bf16* Xb  = (bf16*)(ws);
  bf16* ctx = (bf16*)(ws);
  bf16* Q   = (bf16*)(ws + SZ);
  bf16* Vt  = (bf16*)(ws + 2 * SZ);
  bf16* Wob = (bf16*)(ws + 2 * SZ);
  // d_out hosts bf16 K [0,16M) and Wq/Wk/Wv bf16 [16M,22M) until proj overwrites.
  bf16* Kb  = (bf16*)d_out;
  bf16* Wqb = (bf16*)((char*)d_out + SZ);
  bf16* Wkb = Wqb + 1024 * 1024;
  bf16* Wvb = Wkb + 1024 * 1024;

  const int nX4 = (B_ * S_ * HID_) / 4;    // 2,097,152
  const int nW4 = (HID_ * HID_) / 4;       // 262,144
  cvt_kernel<<<(nX4 + 255) / 256, 256, 0, stream>>>(X, Xb, nX4);
  cvt_kernel<<<(nW4 + 255) / 256, 256, 0, stream>>>(Wq, Wqb, nW4);
  cvt_kernel<<<(nW4 + 255) / 256, 256, 0, stream>>>(Wk, Wkb, nW4);
  cvt_kernel<<<(nW4 + 255) / 256, 256, 0, stream>>>(Wv, Wvb, nW4);

  qkv_gemm<<<dim3(8, 64, 3), 256, 0, stream>>>(Xb, Wqb, Wkb, Wvb, pos, Q, Kb, Vt);
  attn_kernel<<<dim3(32, 64), 256, 0, stream>>>(Q, Kb, Vt, mask, ctx);

  cvt_kernel<<<(nW4 + 255) / 256, 256, 0, stream>>>(Wo, Wob, nW4);
  proj_gemm<<<dim3(8, 64), 256, 0, stream>>>(ctx, Wob, out);
}

// Round 5
// 1412.801 us; speedup vs baseline: 1.0127x; 1.0127x over previous
//
#include <hip/hip_runtime.h>
#include <hip/hip_bf16.h>
#include <math.h>

typedef __bf16 bf16;
typedef bf16 bf16x4 __attribute__((ext_vector_type(4)));
typedef bf16 bf16x8 __attribute__((ext_vector_type(8)));
typedef float f32x4 __attribute__((ext_vector_type(4)));

#define B_ 4
#define S_ 2048
#define HID_ 1024
#define NH_ 16
#define HD_ 64
#define LTS 72   // padded LDS tile stride (16B-aligned rows, staggers banks)

// async global->LDS, 16B per lane. LDS dest must be wave-uniform base + lane*16.
__device__ __forceinline__ void async16(const bf16* g, bf16* l) {
  __builtin_amdgcn_global_load_lds(
      (const __attribute__((address_space(1))) void*)g,
      (__attribute__((address_space(3))) void*)l, 16, 0, 0);
}

// ---------------- fp32 -> bf16 convert (vector: 4 floats -> 4 bf16 per thread)
__global__ void cvt_kernel(const float* __restrict__ src, bf16* __restrict__ dst, int n4) {
  int i = blockIdx.x * 256 + threadIdx.x;
  if (i < n4) {
    float4 v = ((const float4*)src)[i];
    bf16x4 o;
    o[0] = (bf16)v.x; o[1] = (bf16)v.y; o[2] = (bf16)v.z; o[3] = (bf16)v.w;
    ((bf16x4*)dst)[i] = o;
  }
}

// ---------------- QKV GEMM: Y = Xb @ Wb^T  (M=8192, N=1024, K=1024), fused inline RoPE.
// z=0 -> Q (scaled 1/8, RoPE) [B,H,S,D]; z=1 -> K (RoPE) [B,H,S,D]; z=2 -> V^T [B,H,D,S]
// Epilogue round-trips each wave's 64x64 C-tile through LDS so all global
// stores are 16 B/lane with lanes 0..7 covering a full 128 B line-pair.
__global__ __launch_bounds__(256, 2) void qkv_gemm(
    const bf16* __restrict__ X, const bf16* __restrict__ Wq,
    const bf16* __restrict__ Wk, const bf16* __restrict__ Wv,
    const int* __restrict__ pos,
    bf16* __restrict__ Q, bf16* __restrict__ Ko, bf16* __restrict__ Vt) {
  const int z = blockIdx.z;
  const bf16* W = (z == 0) ? Wq : (z == 1) ? Wk : Wv;
  const int m0 = blockIdx.y * 128;
  const int n0 = blockIdx.x * 128;
  __shared__ __align__(16) bf16 lA[128 * 32];
  __shared__ __align__(16) bf16 lB[128 * 32];
  __shared__ __align__(16) bf16 lT[4][64 * LTS];   // per-wave transpose tile
  const int tid = threadIdx.x;
  const int lane = tid & 63, w = tid >> 6;
  const int wm = (w >> 1) * 64, wn = (w & 1) * 64;
  const int quad = lane >> 4, l16 = lane & 15;

  f32x4 acc[4][4] = {};

  const int qa = tid, qb = tid + 256;           // 512 chunks of 8 bf16 per [128][32] tile
  const int ra = qa >> 2, ca = (qa & 3) * 8;
  const int rb = qb >> 2, cb = (qb & 3) * 8;

  for (int k0 = 0; k0 < 1024; k0 += 32) {
    async16(X + (size_t)(m0 + ra) * 1024 + k0 + ca, lA + qa * 8);
    async16(X + (size_t)(m0 + rb) * 1024 + k0 + cb, lA + qb * 8);
    async16(W + (size_t)(n0 + ra) * 1024 + k0 + ca, lB + qa * 8);
    async16(W + (size_t)(n0 + rb) * 1024 + k0 + cb, lB + qb * 8);
    __syncthreads();
    bf16x8 af[4], bfr[4];
#pragma unroll
    for (int i = 0; i < 4; i++)
      af[i] = *(const bf16x8*)(lA + (wm + i * 16 + l16) * 32 + quad * 8);
#pragma unroll
    for (int j = 0; j < 4; j++)
      bfr[j] = *(const bf16x8*)(lB + (wn + j * 16 + l16) * 32 + quad * 8);
#pragma unroll
    for (int i = 0; i < 4; i++)
#pragma unroll
      for (int j = 0; j < 4; j++)
        acc[i][j] = __builtin_amdgcn_mfma_f32_16x16x32_bf16(af[i], bfr[j], acc[i][j], 0, 0, 0);
    __syncthreads();
  }

  // wave-uniform output geometry: this wave covers rows m0+wm..+63 (one b),
  // cols = one head h, d 0..63.
  const int h = (n0 + wn) >> 6;
  const int mbase = m0 + wm;
  const int b = mbase >> 11, s0 = mbase & 2047;
  bf16* myT = lT[w];

  if (z <= 1) {
    // ---- write phase: RoPE in-register, m-major tile [m_loc][d] stride LTS
    const float scl = (z == 0) ? 0.125f : 1.0f;
    const float invf0 = expf(-0.28782313662425572f * (float)l16);         // ln(1e4)/32
    const float invf1 = expf(-0.28782313662425572f * (float)(16 + l16));
#pragma unroll
    for (int i = 0; i < 4; i++)
#pragma unroll
      for (int r = 0; r < 4; r++) {
        int mloc = i * 16 + quad * 4 + r;
        float p = (float)pos[mbase + mloc];
#pragma unroll
        for (int j = 0; j < 2; j++) {      // RoPE pair (d, d+32) = frags (j, j+2)
          int d = j * 16 + l16;
          float a = p * (j == 0 ? invf0 : invf1);
          float cv = cosf(a), sv = sinf(a);
          float lo = acc[i][j][r], hi = acc[i][j + 2][r];
          myT[mloc * LTS + d]      = (bf16)((lo * cv - hi * sv) * scl);
          myT[mloc * LTS + d + 32] = (bf16)((hi * cv + lo * sv) * scl);
        }
      }
    asm volatile("s_waitcnt lgkmcnt(0)" ::: "memory");
    // ---- read phase: lanes 0..7 = one row's 8 chunks -> 128 B contiguous
    bf16* dst = (z == 0) ? Q : Ko;
    const int rr = lane >> 3, cc = lane & 7;
#pragma unroll
    for (int it = 0; it < 8; it++) {
      int mloc = it * 8 + rr;
      bf16x8 v = *(const bf16x8*)(myT + mloc * LTS + cc * 8);
      *(bf16x8*)(dst + (((size_t)b * NH_ + h) * S_ + s0 + mloc) * HD_ + cc * 8) = v;
    }
  } else {
    // ---- write phase: n-major tile [d][m_loc] stride LTS (r-values contiguous)
#pragma unroll
    for (int i = 0; i < 4; i++)
#pragma unroll
      for (int j = 0; j < 4; j++) {
        bf16x4 o;
#pragma unroll
        for (int r = 0; r < 4; r++) o[r] = (bf16)acc[i][j][r];
        *(bf16x4*)(myT + (j * 16 + l16) * LTS + i * 16 + quad * 4) = o;
      }
    asm volatile("s_waitcnt lgkmcnt(0)" ::: "memory");
    // ---- read phase: lanes 0..7 = one d-row's 8 s-chunks -> 128 B contiguous
    const int rr = lane >> 3, cc = lane & 7;
#pragma unroll
    for (int it = 0; it < 8; it++) {
      int d = it * 8 + rr;
      bf16x8 v = *(const bf16x8*)(myT + d * LTS + cc * 8);
      *(bf16x8*)(Vt + (((size_t)b * NH_ + h) * HD_ + d) * S_ + s0 + cc * 8) = v;
    }
  }
}

// ---------------- flash attention: block = (64-row Q tile) x (b,h). K/V tiled by 64.
__global__ __launch_bounds__(256, 2) void attn_kernel(
    const bf16* __restrict__ Q, const bf16* __restrict__ K,
    const bf16* __restrict__ Vt, const float* __restrict__ mask,
    bf16* __restrict__ ctx) {
  const int b = blockIdx.y >> 4, h = blockIdx.y & 15;
  const int q0 = blockIdx.x * 64;
  __shared__ __align__(16) bf16 lQ[64 * 64];    // Q tile; reused as O-transpose tile
  __shared__ __align__(16) bf16 lK[64 * 64];
  __shared__ __align__(16) bf16 lV[64 * 64];    // V^T tile: [d][k]
  __shared__ __align__(16) bf16 lP[4][16 * 64]; // per-wave P: [m(16)][k(64)]
  const int tid = threadIdx.x;
  const int lane = tid & 63, w = tid >> 6;
  const int quad = lane >> 4, l16 = lane & 15;

  const size_t headoff = ((size_t)b * NH_ + h) * S_ * HD_;
  {  // stage Q tile once (contiguous 4096 elems)
    const bf16* src = Q + headoff + (size_t)q0 * HD_;
    async16(src + tid * 8, lQ + tid * 8);
    async16(src + (tid + 256) * 8, lQ + (tid + 256) * 8);
  }

  f32x4 oacc[4] = {};
  float m_run[4] = {-1e30f, -1e30f, -1e30f, -1e30f};
  float l_run[4] = {0.f, 0.f, 0.f, 0.f};

  for (int kt = 0; kt < 32; kt++) {
    const int k0 = kt * 64;
    const bf16* ksrc = K + headoff + (size_t)k0 * HD_;  // contiguous tile
    async16(ksrc + tid * 8, lK + tid * 8);
    async16(ksrc + (tid + 256) * 8, lK + (tid + 256) * 8);
    {
      const bf16* vbase = Vt + headoff;                 // [d][s] rows, stride S_
      async16(vbase + (size_t)(tid >> 3) * S_ + k0 + (tid & 7) * 8, lV + tid * 8);
      async16(vbase + (size_t)((tid + 256) >> 3) * S_ + k0 + ((tid + 256) & 7) * 8,
              lV + (tid + 256) * 8);
    }
    __syncthreads();

    // S = (Q/8) K^T : wave w owns S rows w*16..w*16+15, all 64 cols
    f32x4 sacc[4] = {};
#pragma unroll
    for (int ks = 0; ks < 2; ks++) {
      bf16x8 aq = *(const bf16x8*)(lQ + (w * 16 + l16) * 64 + ks * 32 + quad * 8);
#pragma unroll
      for (int j = 0; j < 4; j++) {
        bf16x8 bk = *(const bf16x8*)(lK + (j * 16 + l16) * 64 + ks * 32 + quad * 8);
        sacc[j] = __builtin_amdgcn_mfma_f32_16x16x32_bf16(aq, bk, sacc[j], 0, 0, 0);
      }
    }
    // mask add (fp32 global) + online softmax; quad's 16 lanes hold one row's cols
    float sv[4][4];
#pragma unroll
    for (int r = 0; r < 4; r++) {
      int qrow = q0 + w * 16 + quad * 4 + r;
      const float* mrow = mask + ((size_t)b * S_ + qrow) * S_ + k0;
#pragma unroll
      for (int j = 0; j < 4; j++)
        sv[j][r] = sacc[j][r] + mrow[j * 16 + l16];
    }
#pragma unroll
    for (int r = 0; r < 4; r++) {
      float mx = fmaxf(fmaxf(sv[0][r], sv[1][r]), fmaxf(sv[2][r], sv[3][r]));
      mx = fmaxf(mx, __shfl_xor(mx, 1));   // masks <16 stay within the quad's 16 lanes
      mx = fmaxf(mx, __shfl_xor(mx, 2));
      mx = fmaxf(mx, __shfl_xor(mx, 4));
      mx = fmaxf(mx, __shfl_xor(mx, 8));
      float mnew = fmaxf(m_run[r], mx);
      float alpha = expf(m_run[r] - mnew);
      m_run[r] = mnew;
      float psum = 0.f;
#pragma unroll
      for (int j = 0; j < 4; j++) {
        float p = expf(sv[j][r] - mnew);
        psum += p;
        lP[w][(quad * 4 + r) * 64 + j * 16 + l16] = (bf16)p;  // C/D -> LDS
      }
      psum += __shfl_xor(psum, 1);
      psum += __shfl_xor(psum, 2);
      psum += __shfl_xor(psum, 4);
      psum += __shfl_xor(psum, 8);
      l_run[r] = l_run[r] * alpha + psum;
#pragma unroll
      for (int j = 0; j < 4; j++) oacc[j][r] *= alpha;
    }
    // O += P @ V  (A-layout read of P from LDS; lV rows are d, k-contiguous)
#pragma unroll
    for (int ks = 0; ks < 2; ks++) {
      bf16x8 ap = *(const bf16x8*)(&lP[w][l16 * 64 + ks * 32 + quad * 8]);
#pragma unroll
      for (int j = 0; j < 4; j++) {
        bf16x8 bv = *(const bf16x8*)(lV + (j * 16 + l16) * 64 + ks * 32 + quad * 8);
        oacc[j] = __builtin_amdgcn_mfma_f32_16x16x32_bf16(ap, bv, oacc[j], 0, 0, 0);
      }
    }
    __syncthreads();
  }

  // normalize + coalesced ctx store: O tile (64 s x 64 d) through lQ (dead now)
#pragma unroll
  for (int r = 0; r < 4; r++) {
    float invl = 1.0f / l_run[r];
    int sloc = w * 16 + quad * 4 + r;
#pragma unroll
    for (int j = 0; j < 4; j++)
      lQ[sloc * 64 + j * 16 + l16] = (bf16)(oacc[j][r] * invl);
  }
  __syncthreads();
  {
    const int rr = tid >> 3, cc = tid & 7;   // 32 rows per pass, 2 passes
#pragma unroll
    for (int it = 0; it < 2; it++) {
      int sloc = it * 32 + rr;
      bf16x8 v = *(const bf16x8*)(lQ + sloc * 64 + cc * 8);
      *(bf16x8*)(ctx + ((size_t)b * S_ + q0 + sloc) * HID_ + h * HD_ + cc * 8) = v;
    }
  }
}

// ---------------- output projection: out(fp32) = ctx @ Wo^T
__global__ __launch_bounds__(256, 2) void proj_gemm(
    const bf16* __restrict__ A, const bf16* __restrict__ Wo, float* __restrict__ out) {
  const int m0 = blockIdx.y * 128;
  const int n0 = blockIdx.x * 128;
  __shared__ __align__(16) bf16 lA[128 * 32];
  __shared__ __align__(16) bf16 lB[128 * 32];
  const int tid = threadIdx.x;
  const int lane = tid & 63, w = tid >> 6;
  const int wm = (w >> 1) * 64, wn = (w & 1) * 64;
  const int quad = lane >> 4, l16 = lane & 15;

  f32x4 acc[4][4] = {};
  const int qa = tid, qb = tid + 256;
  const int ra = qa >> 2, ca = (qa & 3) * 8;
  const int rb = qb >> 2, cb = (qb & 3) * 8;

  for (int k0 = 0; k0 < 1024; k0 += 32) {
    async16(A + (size_t)(m0 + ra) * 1024 + k0 + ca, lA + qa * 8);
    async16(A + (size_t)(m0 + rb) * 1024 + k0 + cb, lA + qb * 8);
    async16(Wo + (size_t)(n0 + ra) * 1024 + k0 + ca, lB + qa * 8);
    async16(Wo + (size_t)(n0 + rb) * 1024 + k0 + cb, lB + qb * 8);
    __syncthreads();
    bf16x8 af[4], bfr[4];
#pragma unroll
    for (int i = 0; i < 4; i++)
      af[i] = *(const bf16x8*)(lA + (wm + i * 16 + l16) * 32 + quad * 8);
#pragma unroll
    for (int j = 0; j < 4; j++)
      bfr[j] = *(const bf16x8*)(lB + (wn + j * 16 + l16) * 32 + quad * 8);
#pragma unroll
    for (int i = 0; i < 4; i++)
#pragma unroll
      for (int j = 0; j < 4; j++)
        acc[i][j] = __builtin_amdgcn_mfma_f32_16x16x32_bf16(af[i], bfr[j], acc[i][j], 0, 0, 0);
    __syncthreads();
  }
#pragma unroll
  for (int i = 0; i < 4; i++)
#pragma unroll
    for (int r = 0; r < 4; r++) {
      int m = m0 + wm + i * 16 + quad * 4 + r;
#pragma unroll
      for (int j = 0; j < 4; j++)
        out[(size_t)m * 1024 + n0 + wn + j * 16 + l16] = acc[i][j][r];
    }
}

// ---------------- loud-failure sentinel: encodes ws MiB into the output
__global__ void sentinel_kernel(float* out, int n, float val) {
  int i = blockIdx.x * 256 + threadIdx.x;
  if (i < n) out[i] = val;
}

extern "C" void kernel_launch(void* const* d_in, const int* in_sizes, int n_in,
                              void* d_out, int out_size, void* d_ws, size_t ws_size,
                              hipStream_t stream) {
  const float* X    = (const float*)d_in[0];  // [4,2048,1024]
  const float* mask = (const float*)d_in[1];  // [4,1,2048,2048]
  const int*   pos  = (const int*)d_in[2];    // [4,2048]
  const float* Wq   = (const float*)d_in[3];
  const float* Wk   = (const float*)d_in[4];
  const float* Wv   = (const float*)d_in[5];
  const float* Wo   = (const float*)d_in[6];
  float* out = (float*)d_out;                 // [4,2048,1024] fp32 = 32 MiB

  char* ws = (char*)d_ws;
  const size_t SZ = (size_t)B_ * NH_ * S_ * HD_ * sizeof(bf16);  // 16 MiB
  if (ws_size < 3 * SZ) {
    sentinel_kernel<<<(out_size + 255) / 256, 256, 0, stream>>>(
        out, out_size, (float)(ws_size >> 20));
    return;
  }

  // ws layout (48 MiB): [0,16M) Xb then ctx; [16M,32M) Q; [32M,48M) Vt then Wob.
  bf16* Xb  = (bf16*)(ws);
  bf16* ctx = (bf16*)(ws);
  bf16* Q   = (bf16*)(ws + SZ);
  bf16* Vt  = (bf16*)(ws + 2 * SZ);
  bf16* Wob = (bf16*)(ws + 2 * SZ);
  // d_out hosts bf16 K [0,16M) and Wq/Wk/Wv bf16 [16M,22M) until proj overwrites.
  bf16* Kb  = (bf16*)d_out;
  bf16* Wqb = (bf16*)((char*)d_out + SZ);
  bf16* Wkb = Wqb + 1024 * 1024;
  bf16* Wvb = Wkb + 1024 * 1024;

  const int nX4 = (B_ * S_ * HID_) / 4;
  const int nW4 = (HID_ * HID_) / 4;
  cvt_kernel<<<(nX4 + 255) / 256, 256, 0, stream>>>(X, Xb, nX4);
  cvt_kernel<<<(nW4 + 255) / 256, 256, 0, stream>>>(Wq, Wqb, nW4);
  cvt_kernel<<<(nW4 + 255) / 256, 256, 0, stream>>>(Wk, Wkb, nW4);
  cvt_kernel<<<(nW4 + 255) / 256, 256, 0, stream>>>(Wv, Wvb, nW4);

  qkv_gemm<<<dim3(8, 64, 3), 256, 0, stream>>>(Xb, Wqb, Wkb, Wvb, pos, Q, Kb, Vt);
  attn_kernel<<<dim3(32, 64), 256, 0, stream>>>(Q, Kb, Vt, mask, ctx);

  cvt_kernel<<<(nW4 + 255) / 256, 256, 0, stream>>>(Wo, Wob, nW4);
  proj_gemm<<<dim3(8, 64), 256, 0, stream>>>(ctx, Wob, out);
}

// Round 6
// 582.573 us; speedup vs baseline: 2.4558x; 2.4251x over previous
//
#include <hip/hip_runtime.h>
#include <hip/hip_bf16.h>
#include <math.h>

typedef __bf16 bf16;
typedef bf16 bf16x4 __attribute__((ext_vector_type(4)));
typedef bf16 bf16x8 __attribute__((ext_vector_type(8)));
typedef float f32x4 __attribute__((ext_vector_type(4)));

#define B_ 4
#define S_ 2048
#define HID_ 1024
#define NH_ 16
#define HD_ 64
#define LTS 72   // padded LDS tile stride

// async global->LDS, 16B per lane. LDS dest must be wave-uniform base + lane*16.
__device__ __forceinline__ void async16(const bf16* g, bf16* l) {
  __builtin_amdgcn_global_load_lds(
      (const __attribute__((address_space(1))) void*)g,
      (__attribute__((address_space(3))) void*)l, 16, 0, 0);
}

#define MM16(A, B, C) C = __builtin_amdgcn_mfma_f32_16x16x32_bf16(A, B, C, 0, 0, 0)

// ---------------- fp32 -> bf16 convert
__global__ void cvt_kernel(const float* __restrict__ src, bf16* __restrict__ dst, int n4) {
  int i = blockIdx.x * 256 + threadIdx.x;
  if (i < n4) {
    float4 v = ((const float4*)src)[i];
    bf16x4 o;
    o[0] = (bf16)v.x; o[1] = (bf16)v.y; o[2] = (bf16)v.z; o[3] = (bf16)v.w;
    ((bf16x4*)dst)[i] = o;
  }
}

// K-loop body shared by qkv/proj: declare named accs, frag loads, 16 MFMAs.
#define DECL_ACC \
  f32x4 a00 = {}, a01 = {}, a02 = {}, a03 = {}; \
  f32x4 a10 = {}, a11 = {}, a12 = {}, a13 = {}; \
  f32x4 a20 = {}, a21 = {}, a22 = {}, a23 = {}; \
  f32x4 a30 = {}, a31 = {}, a32 = {}, a33 = {};

#define KLOOP_FRAGS_MFMA \
    bf16x8 af0 = *(const bf16x8*)(lA + (wm + 0 * 16 + l16) * 32 + quad * 8); \
    bf16x8 af1 = *(const bf16x8*)(lA + (wm + 1 * 16 + l16) * 32 + quad * 8); \
    bf16x8 af2 = *(const bf16x8*)(lA + (wm + 2 * 16 + l16) * 32 + quad * 8); \
    bf16x8 af3 = *(const bf16x8*)(lA + (wm + 3 * 16 + l16) * 32 + quad * 8); \
    bf16x8 bg0 = *(const bf16x8*)(lB + (wn + 0 * 16 + l16) * 32 + quad * 8); \
    bf16x8 bg1 = *(const bf16x8*)(lB + (wn + 1 * 16 + l16) * 32 + quad * 8); \
    bf16x8 bg2 = *(const bf16x8*)(lB + (wn + 2 * 16 + l16) * 32 + quad * 8); \
    bf16x8 bg3 = *(const bf16x8*)(lB + (wn + 3 * 16 + l16) * 32 + quad * 8); \
    MM16(af0, bg0, a00); MM16(af0, bg1, a01); MM16(af0, bg2, a02); MM16(af0, bg3, a03); \
    MM16(af1, bg0, a10); MM16(af1, bg1, a11); MM16(af1, bg2, a12); MM16(af1, bg3, a13); \
    MM16(af2, bg0, a20); MM16(af2, bg1, a21); MM16(af2, bg2, a22); MM16(af2, bg3, a23); \
    MM16(af3, bg0, a30); MM16(af3, bg1, a31); MM16(af3, bg2, a32); MM16(af3, bg3, a33);

// RoPE epilogue per (i, r): C0..C3 are the 4 j-fragments of row block i.
#define ROPE_R(i, r, C0, C1, C2, C3) { \
  const int mloc = (i) * 16 + quad * 4 + (r); \
  const float p = (float)pos[mbase + mloc]; \
  const float aa0 = p * invf0, aa1 = p * invf1; \
  const float c0 = cosf(aa0), sn0 = sinf(aa0); \
  const float c1 = cosf(aa1), sn1 = sinf(aa1); \
  myT[mloc * LTS + l16]      = (bf16)((C0[r] * c0 - C2[r] * sn0) * scl); \
  myT[mloc * LTS + 32 + l16] = (bf16)((C2[r] * c0 + C0[r] * sn0) * scl); \
  myT[mloc * LTS + 16 + l16] = (bf16)((C1[r] * c1 - C3[r] * sn1) * scl); \
  myT[mloc * LTS + 48 + l16] = (bf16)((C3[r] * c1 + C1[r] * sn1) * scl); }
#define ROPE_I(i, C0, C1, C2, C3) \
  ROPE_R(i, 0, C0, C1, C2, C3) ROPE_R(i, 1, C0, C1, C2, C3) \
  ROPE_R(i, 2, C0, C1, C2, C3) ROPE_R(i, 3, C0, C1, C2, C3)

// V epilogue per (i, j): write 4 r-contiguous values into n-major tile.
#define VW(i, j, C) { \
  bf16x4 o; o[0] = (bf16)C[0]; o[1] = (bf16)C[1]; o[2] = (bf16)C[2]; o[3] = (bf16)C[3]; \
  *(bf16x4*)(myT + ((j) * 16 + l16) * LTS + (i) * 16 + quad * 4) = o; }

// ---------------- QKV GEMM: Y = Xb @ Wb^T, fused RoPE.
// z=0 -> Q (1/8, RoPE) [B,H,S,D]; z=1 -> K (RoPE) [B,H,S,D]; z=2 -> V^T [B,H,D,S]
__global__ void qkv_gemm(
    const bf16* __restrict__ X, const bf16* __restrict__ Wq,
    const bf16* __restrict__ Wk, const bf16* __restrict__ Wv,
    const int* __restrict__ pos,
    bf16* __restrict__ Q, bf16* __restrict__ Ko, bf16* __restrict__ Vt) {
  const int z = blockIdx.z;
  const bf16* W = (z == 0) ? Wq : (z == 1) ? Wk : Wv;
  const int m0 = blockIdx.y * 128;
  const int n0 = blockIdx.x * 128;
  __shared__ __align__(16) bf16 lA[128 * 32];
  __shared__ __align__(16) bf16 lB[128 * 32];
  __shared__ __align__(16) bf16 lT[4][64 * LTS];
  const int tid = threadIdx.x;
  const int lane = tid & 63, w = tid >> 6;
  const int wm = (w >> 1) * 64, wn = (w & 1) * 64;
  const int quad = lane >> 4, l16 = lane & 15;

  DECL_ACC

  const int qa = tid, qb = tid + 256;
  const int ra = qa >> 2, ca = (qa & 3) * 8;
  const int rb = qb >> 2, cb = (qb & 3) * 8;

  for (int k0 = 0; k0 < 1024; k0 += 32) {
    async16(X + (size_t)(m0 + ra) * 1024 + k0 + ca, lA + qa * 8);
    async16(X + (size_t)(m0 + rb) * 1024 + k0 + cb, lA + qb * 8);
    async16(W + (size_t)(n0 + ra) * 1024 + k0 + ca, lB + qa * 8);
    async16(W + (size_t)(n0 + rb) * 1024 + k0 + cb, lB + qb * 8);
    __syncthreads();
    KLOOP_FRAGS_MFMA
    __syncthreads();
  }

  const int h = (n0 + wn) >> 6;
  const int mbase = m0 + wm;
  const int b = mbase >> 11, s0 = mbase & 2047;
  bf16* myT = lT[w];

  if (z <= 1) {
    const float scl = (z == 0) ? 0.125f : 1.0f;
    const float invf0 = expf(-0.28782313662425572f * (float)l16);   // ln(1e4)/32
    const float invf1 = expf(-0.28782313662425572f * (float)(16 + l16));
    ROPE_I(0, a00, a01, a02, a03)
    ROPE_I(1, a10, a11, a12, a13)
    ROPE_I(2, a20, a21, a22, a23)
    ROPE_I(3, a30, a31, a32, a33)
    asm volatile("s_waitcnt lgkmcnt(0)" ::: "memory");
    bf16* dst = (z == 0) ? Q : Ko;
    const int rr = lane >> 3, cc = lane & 7;
#pragma unroll
    for (int it = 0; it < 8; it++) {
      int mloc = it * 8 + rr;
      bf16x8 v = *(const bf16x8*)(myT + mloc * LTS + cc * 8);
      *(bf16x8*)(dst + (((size_t)b * NH_ + h) * S_ + s0 + mloc) * HD_ + cc * 8) = v;
    }
  } else {
    VW(0, 0, a00) VW(0, 1, a01) VW(0, 2, a02) VW(0, 3, a03)
    VW(1, 0, a10) VW(1, 1, a11) VW(1, 2, a12) VW(1, 3, a13)
    VW(2, 0, a20) VW(2, 1, a21) VW(2, 2, a22) VW(2, 3, a23)
    VW(3, 0, a30) VW(3, 1, a31) VW(3, 2, a32) VW(3, 3, a33)
    asm volatile("s_waitcnt lgkmcnt(0)" ::: "memory");
    const int rr = lane >> 3, cc = lane & 7;
#pragma unroll
    for (int it = 0; it < 8; it++) {
      int d = it * 8 + rr;
      bf16x8 v = *(const bf16x8*)(myT + d * LTS + cc * 8);
      *(bf16x8*)(Vt + (((size_t)b * NH_ + h) * HD_ + d) * S_ + s0 + cc * 8) = v;
    }
  }
}

// online-softmax row step; MR/LR are named float lvalues, s0..s3/o0..o3 in scope
#define SM_ROW(r, MR, LR) { \
  const int qrow = q0 + w * 16 + quad * 4 + (r); \
  const float* mrow = mask + ((size_t)b * S_ + qrow) * S_ + k0; \
  float v0 = s0[r] + mrow[l16]; \
  float v1 = s1[r] + mrow[16 + l16]; \
  float v2 = s2[r] + mrow[32 + l16]; \
  float v3 = s3[r] + mrow[48 + l16]; \
  float mx = fmaxf(fmaxf(v0, v1), fmaxf(v2, v3)); \
  mx = fmaxf(mx, __shfl_xor(mx, 1)); \
  mx = fmaxf(mx, __shfl_xor(mx, 2)); \
  mx = fmaxf(mx, __shfl_xor(mx, 4)); \
  mx = fmaxf(mx, __shfl_xor(mx, 8)); \
  const float mnew = fmaxf(MR, mx); \
  const float alpha = expf(MR - mnew); \
  MR = mnew; \
  const float p0 = expf(v0 - mnew), p1 = expf(v1 - mnew); \
  const float p2 = expf(v2 - mnew), p3 = expf(v3 - mnew); \
  bf16* lpr = &lP[w][(quad * 4 + (r)) * 64 + l16]; \
  lpr[0] = (bf16)p0; lpr[16] = (bf16)p1; lpr[32] = (bf16)p2; lpr[48] = (bf16)p3; \
  float ps = p0 + p1 + p2 + p3; \
  ps += __shfl_xor(ps, 1); ps += __shfl_xor(ps, 2); \
  ps += __shfl_xor(ps, 4); ps += __shfl_xor(ps, 8); \
  LR = LR * alpha + ps; \
  o0[r] *= alpha; o1[r] *= alpha; o2[r] *= alpha; o3[r] *= alpha; }

#define OST(r, LR) { \
  const float invl = 1.0f / LR; \
  const int sloc = w * 16 + quad * 4 + (r); \
  lQ[sloc * 64 + l16]      = (bf16)(o0[r] * invl); \
  lQ[sloc * 64 + 16 + l16] = (bf16)(o1[r] * invl); \
  lQ[sloc * 64 + 32 + l16] = (bf16)(o2[r] * invl); \
  lQ[sloc * 64 + 48 + l16] = (bf16)(o3[r] * invl); }

// ---------------- flash attention: block = (64-row Q tile) x (b,h). K/V tiled by 64.
__global__ void attn_kernel(
    const bf16* __restrict__ Q, const bf16* __restrict__ K,
    const bf16* __restrict__ Vt, const float* __restrict__ mask,
    bf16* __restrict__ ctx) {
  const int b = blockIdx.y >> 4, h = blockIdx.y & 15;
  const int q0 = blockIdx.x * 64;
  __shared__ __align__(16) bf16 lQ[64 * 64];    // Q tile; reused as O-transpose tile
  __shared__ __align__(16) bf16 lK[64 * 64];
  __shared__ __align__(16) bf16 lV[64 * 64];    // V^T tile: [d][k]
  __shared__ __align__(16) bf16 lP[4][16 * 64]; // per-wave P: [m(16)][k(64)]
  const int tid = threadIdx.x;
  const int lane = tid & 63, w = tid >> 6;
  const int quad = lane >> 4, l16 = lane & 15;

  const size_t headoff = ((size_t)b * NH_ + h) * S_ * HD_;
  {
    const bf16* src = Q + headoff + (size_t)q0 * HD_;
    async16(src + tid * 8, lQ + tid * 8);
    async16(src + (tid + 256) * 8, lQ + (tid + 256) * 8);
  }

  f32x4 o0 = {}, o1 = {}, o2 = {}, o3 = {};
  float mr0 = -1e30f, mr1 = -1e30f, mr2 = -1e30f, mr3 = -1e30f;
  float lr0 = 0.f, lr1 = 0.f, lr2 = 0.f, lr3 = 0.f;

  for (int kt = 0; kt < 32; kt++) {
    const int k0 = kt * 64;
    const bf16* ksrc = K + headoff + (size_t)k0 * HD_;
    async16(ksrc + tid * 8, lK + tid * 8);
    async16(ksrc + (tid + 256) * 8, lK + (tid + 256) * 8);
    {
      const bf16* vbase = Vt + headoff;
      async16(vbase + (size_t)(tid >> 3) * S_ + k0 + (tid & 7) * 8, lV + tid * 8);
      async16(vbase + (size_t)((tid + 256) >> 3) * S_ + k0 + ((tid + 256) & 7) * 8,
              lV + (tid + 256) * 8);
    }
    __syncthreads();

    // S = (Q/8) K^T
    f32x4 s0 = {}, s1 = {}, s2 = {}, s3 = {};
    {
      bf16x8 aq = *(const bf16x8*)(lQ + (w * 16 + l16) * 64 + quad * 8);
      bf16x8 b0 = *(const bf16x8*)(lK + (0 * 16 + l16) * 64 + quad * 8);
      bf16x8 b1 = *(const bf16x8*)(lK + (1 * 16 + l16) * 64 + quad * 8);
      bf16x8 b2 = *(const bf16x8*)(lK + (2 * 16 + l16) * 64 + quad * 8);
      bf16x8 b3 = *(const bf16x8*)(lK + (3 * 16 + l16) * 64 + quad * 8);
      MM16(aq, b0, s0); MM16(aq, b1, s1); MM16(aq, b2, s2); MM16(aq, b3, s3);
    }
    {
      bf16x8 aq = *(const bf16x8*)(lQ + (w * 16 + l16) * 64 + 32 + quad * 8);
      bf16x8 b0 = *(const bf16x8*)(lK + (0 * 16 + l16) * 64 + 32 + quad * 8);
      bf16x8 b1 = *(const bf16x8*)(lK + (1 * 16 + l16) * 64 + 32 + quad * 8);
      bf16x8 b2 = *(const bf16x8*)(lK + (2 * 16 + l16) * 64 + 32 + quad * 8);
      bf16x8 b3 = *(const bf16x8*)(lK + (3 * 16 + l16) * 64 + 32 + quad * 8);
      MM16(aq, b0, s0); MM16(aq, b1, s1); MM16(aq, b2, s2); MM16(aq, b3, s3);
    }

    SM_ROW(0, mr0, lr0)
    SM_ROW(1, mr1, lr1)
    SM_ROW(2, mr2, lr2)
    SM_ROW(3, mr3, lr3)

    // O += P @ V
    {
      bf16x8 ap = *(const bf16x8*)(&lP[w][l16 * 64 + quad * 8]);
      bf16x8 b0 = *(const bf16x8*)(lV + (0 * 16 + l16) * 64 + quad * 8);
      bf16x8 b1 = *(const bf16x8*)(lV + (1 * 16 + l16) * 64 + quad * 8);
      bf16x8 b2 = *(const bf16x8*)(lV + (2 * 16 + l16) * 64 + quad * 8);
      bf16x8 b3 = *(const bf16x8*)(lV + (3 * 16 + l16) * 64 + quad * 8);
      MM16(ap, b0, o0); MM16(ap, b1, o1); MM16(ap, b2, o2); MM16(ap, b3, o3);
    }
    {
      bf16x8 ap = *(const bf16x8*)(&lP[w][l16 * 64 + 32 + quad * 8]);
      bf16x8 b0 = *(const bf16x8*)(lV + (0 * 16 + l16) * 64 + 32 + quad * 8);
      bf16x8 b1 = *(const bf16x8*)(lV + (1 * 16 + l16) * 64 + 32 + quad * 8);
      bf16x8 b2 = *(const bf16x8*)(lV + (2 * 16 + l16) * 64 + 32 + quad * 8);
      bf16x8 b3 = *(const bf16x8*)(lV + (3 * 16 + l16) * 64 + 32 + quad * 8);
      MM16(ap, b0, o0); MM16(ap, b1, o1); MM16(ap, b2, o2); MM16(ap, b3, o3);
    }
    __syncthreads();
  }

  OST(0, lr0) OST(1, lr1) OST(2, lr2) OST(3, lr3)
  __syncthreads();
  {
    const int rr = tid >> 3, cc = tid & 7;
#pragma unroll
    for (int it = 0; it < 2; it++) {
      int sloc = it * 32 + rr;
      bf16x8 v = *(const bf16x8*)(lQ + sloc * 64 + cc * 8);
      *(bf16x8*)(ctx + ((size_t)b * S_ + q0 + sloc) * HID_ + h * HD_ + cc * 8) = v;
    }
  }
}

#define PW(i, j, C) { \
  float* po = out + (size_t)(m0 + wm + (i) * 16 + quad * 4) * 1024 + n0 + wn + (j) * 16 + l16; \
  po[0] = C[0]; po[1024] = C[1]; po[2048] = C[2]; po[3072] = C[3]; }

// ---------------- output projection: out(fp32) = ctx @ Wo^T
__global__ void proj_gemm(
    const bf16* __restrict__ A, const bf16* __restrict__ Wo, float* __restrict__ out) {
  const int m0 = blockIdx.y * 128;
  const int n0 = blockIdx.x * 128;
  __shared__ __align__(16) bf16 lA[128 * 32];
  __shared__ __align__(16) bf16 lB[128 * 32];
  const int tid = threadIdx.x;
  const int lane = tid & 63, w = tid >> 6;
  const int wm = (w >> 1) * 64, wn = (w & 1) * 64;
  const int quad = lane >> 4, l16 = lane & 15;

  DECL_ACC
  const int qa = tid, qb = tid + 256;
  const int ra = qa >> 2, ca = (qa & 3) * 8;
  const int rb = qb >> 2, cb = (qb & 3) * 8;

  for (int k0 = 0; k0 < 1024; k0 += 32) {
    async16(A + (size_t)(m0 + ra) * 1024 + k0 + ca, lA + qa * 8);
    async16(A + (size_t)(m0 + rb) * 1024 + k0 + cb, lA + qb * 8);
    async16(Wo + (size_t)(n0 + ra) * 1024 + k0 + ca, lB + qa * 8);
    async16(Wo + (size_t)(n0 + rb) * 1024 + k0 + cb, lB + qb * 8);
    __syncthreads();
    KLOOP_FRAGS_MFMA
    __syncthreads();
  }
  PW(0, 0, a00) PW(0, 1, a01) PW(0, 2, a02) PW(0, 3, a03)
  PW(1, 0, a10) PW(1, 1, a11) PW(1, 2, a12) PW(1, 3, a13)
  PW(2, 0, a20) PW(2, 1, a21) PW(2, 2, a22) PW(2, 3, a23)
  PW(3, 0, a30) PW(3, 1, a31) PW(3, 2, a32) PW(3, 3, a33)
}

__global__ void sentinel_kernel(float* out, int n, float val) {
  int i = blockIdx.x * 256 + threadIdx.x;
  if (i < n) out[i] = val;
}

extern "C" void kernel_launch(void* const* d_in, const int* in_sizes, int n_in,
                              void* d_out, int out_size, void* d_ws, size_t ws_size,
                              hipStream_t stream) {
  const float* X    = (const float*)d_in[0];
  const float* mask = (const float*)d_in[1];
  const int*   pos  = (const int*)d_in[2];
  const float* Wq   = (const float*)d_in[3];
  const float* Wk   = (const float*)d_in[4];
  const float* Wv   = (const float*)d_in[5];
  const float* Wo   = (const float*)d_in[6];
  float* out = (float*)d_out;

  char* ws = (char*)d_ws;
  const size_t SZ = (size_t)B_ * NH_ * S_ * HD_ * sizeof(bf16);  // 16 MiB
  if (ws_size < 3 * SZ) {
    sentinel_kernel<<<(out_size + 255) / 256, 256, 0, stream>>>(
        out, out_size, (float)(ws_size >> 20));
    return;
  }

  // ws layout (48 MiB): [0,16M) Xb then ctx; [16M,32M) Q; [32M,48M) Vt then Wob.
  bf16* Xb  = (bf16*)(ws);
  bf16* ctx = (bf16*)(ws);
  bf16* Q   = (bf16*)(ws + SZ);
  bf16* Vt  = (bf16*)(ws + 2 * SZ);
  bf16* Wob = (bf16*)(ws + 2 * SZ);
  // d_out hosts bf16 K [0,16M) and Wq/Wk/Wv bf16 [16M,22M) until proj overwrites.
  bf16* Kb  = (bf16*)d_out;
  bf16* Wqb = (bf16*)((char*)d_out + SZ);
  bf16* Wkb = Wqb + 1024 * 1024;
  bf16* Wvb = Wkb + 1024 * 1024;

  const int nX4 = (B_ * S_ * HID_) / 4;
  const int nW4 = (HID_ * HID_) / 4;
  cvt_kernel<<<(nX4 + 255) / 256, 256, 0, stream>>>(X, Xb, nX4);
  cvt_kernel<<<(nW4 + 255) / 256, 256, 0, stream>>>(Wq, Wqb, nW4);
  cvt_kernel<<<(nW4 + 255) / 256, 256, 0, stream>>>(Wk, Wkb, nW4);
  cvt_kernel<<<(nW4 + 255) / 256, 256, 0, stream>>>(Wv, Wvb, nW4);

  qkv_gemm<<<dim3(8, 64, 3), 256, 0, stream>>>(Xb, Wqb, Wkb, Wvb, pos, Q, Kb, Vt);
  attn_kernel<<<dim3(32, 64), 256, 0, stream>>>(Q, Kb, Vt, mask, ctx);

  cvt_kernel<<<(nW4 + 255) / 256, 256, 0, stream>>>(Wo, Wob, nW4);
  proj_gemm<<<dim3(8, 64), 256, 0, stream>>>(ctx, Wob, out);
}

// Round 7
// 498.409 us; speedup vs baseline: 2.8706x; 1.1689x over previous
//
#include <hip/hip_runtime.h>
#include <hip/hip_bf16.h>
#include <math.h>

typedef __bf16 bf16;
typedef bf16 bf16x4 __attribute__((ext_vector_type(4)));
typedef bf16 bf16x8 __attribute__((ext_vector_type(8)));
typedef float f32x4 __attribute__((ext_vector_type(4)));

#define B_ 4
#define S_ 2048
#define HID_ 1024
#define NH_ 16
#define HD_ 64
#define LTS 72   // padded LDS tile stride

// async global->LDS, 16B per lane. LDS dest must be wave-uniform base + lane*16.
__device__ __forceinline__ void async16(const bf16* g, bf16* l) {
  __builtin_amdgcn_global_load_lds(
      (const __attribute__((address_space(1))) void*)g,
      (__attribute__((address_space(3))) void*)l, 16, 0, 0);
}

#define MM16(A, B, C) C = __builtin_amdgcn_mfma_f32_16x16x32_bf16(A, B, C, 0, 0, 0)

// ---------------- fp32 -> bf16 convert
__global__ void cvt_kernel(const float* __restrict__ src, bf16* __restrict__ dst, int n4) {
  int i = blockIdx.x * 256 + threadIdx.x;
  if (i < n4) {
    float4 v = ((const float4*)src)[i];
    bf16x4 o;
    o[0] = (bf16)v.x; o[1] = (bf16)v.y; o[2] = (bf16)v.z; o[3] = (bf16)v.w;
    ((bf16x4*)dst)[i] = o;
  }
}

// K-loop body shared by qkv/proj: named accs, frag loads, 16 MFMAs.
#define DECL_ACC \
  f32x4 a00 = {}, a01 = {}, a02 = {}, a03 = {}; \
  f32x4 a10 = {}, a11 = {}, a12 = {}, a13 = {}; \
  f32x4 a20 = {}, a21 = {}, a22 = {}, a23 = {}; \
  f32x4 a30 = {}, a31 = {}, a32 = {}, a33 = {};

#define KLOOP_FRAGS_MFMA \
    bf16x8 af0 = *(const bf16x8*)(lA + (wm + 0 * 16 + l16) * 32 + quad * 8); \
    bf16x8 af1 = *(const bf16x8*)(lA + (wm + 1 * 16 + l16) * 32 + quad * 8); \
    bf16x8 af2 = *(const bf16x8*)(lA + (wm + 2 * 16 + l16) * 32 + quad * 8); \
    bf16x8 af3 = *(const bf16x8*)(lA + (wm + 3 * 16 + l16) * 32 + quad * 8); \
    bf16x8 bg0 = *(const bf16x8*)(lB + (wn + 0 * 16 + l16) * 32 + quad * 8); \
    bf16x8 bg1 = *(const bf16x8*)(lB + (wn + 1 * 16 + l16) * 32 + quad * 8); \
    bf16x8 bg2 = *(const bf16x8*)(lB + (wn + 2 * 16 + l16) * 32 + quad * 8); \
    bf16x8 bg3 = *(const bf16x8*)(lB + (wn + 3 * 16 + l16) * 32 + quad * 8); \
    MM16(af0, bg0, a00); MM16(af0, bg1, a01); MM16(af0, bg2, a02); MM16(af0, bg3, a03); \
    MM16(af1, bg0, a10); MM16(af1, bg1, a11); MM16(af1, bg2, a12); MM16(af1, bg3, a13); \
    MM16(af2, bg0, a20); MM16(af2, bg1, a21); MM16(af2, bg2, a22); MM16(af2, bg3, a23); \
    MM16(af3, bg0, a30); MM16(af3, bg1, a31); MM16(af3, bg2, a32); MM16(af3, bg3, a33);

// RoPE epilogue per (i, r)
#define ROPE_R(i, r, C0, C1, C2, C3) { \
  const int mloc = (i) * 16 + quad * 4 + (r); \
  const float p = (float)pos[mbase + mloc]; \
  const float aa0 = p * invf0, aa1 = p * invf1; \
  const float c0 = cosf(aa0), sn0 = sinf(aa0); \
  const float c1 = cosf(aa1), sn1 = sinf(aa1); \
  myT[mloc * LTS + l16]      = (bf16)((C0[r] * c0 - C2[r] * sn0) * scl); \
  myT[mloc * LTS + 32 + l16] = (bf16)((C2[r] * c0 + C0[r] * sn0) * scl); \
  myT[mloc * LTS + 16 + l16] = (bf16)((C1[r] * c1 - C3[r] * sn1) * scl); \
  myT[mloc * LTS + 48 + l16] = (bf16)((C3[r] * c1 + C1[r] * sn1) * scl); }
#define ROPE_I(i, C0, C1, C2, C3) \
  ROPE_R(i, 0, C0, C1, C2, C3) ROPE_R(i, 1, C0, C1, C2, C3) \
  ROPE_R(i, 2, C0, C1, C2, C3) ROPE_R(i, 3, C0, C1, C2, C3)

#define VW(i, j, C) { \
  bf16x4 o; o[0] = (bf16)C[0]; o[1] = (bf16)C[1]; o[2] = (bf16)C[2]; o[3] = (bf16)C[3]; \
  *(bf16x4*)(myT + ((j) * 16 + l16) * LTS + (i) * 16 + quad * 4) = o; }

// ---------------- QKV GEMM: Y = Xb @ Wb^T, fused RoPE.
__global__ void qkv_gemm(
    const bf16* __restrict__ X, const bf16* __restrict__ Wq,
    const bf16* __restrict__ Wk, const bf16* __restrict__ Wv,
    const int* __restrict__ pos,
    bf16* __restrict__ Q, bf16* __restrict__ Ko, bf16* __restrict__ Vt) {
  const int z = blockIdx.z;
  const bf16* W = (z == 0) ? Wq : (z == 1) ? Wk : Wv;
  const int m0 = blockIdx.y * 128;
  const int n0 = blockIdx.x * 128;
  __shared__ __align__(16) bf16 lA[128 * 32];
  __shared__ __align__(16) bf16 lB[128 * 32];
  __shared__ __align__(16) bf16 lT[4][64 * LTS];
  const int tid = threadIdx.x;
  const int lane = tid & 63, w = tid >> 6;
  const int wm = (w >> 1) * 64, wn = (w & 1) * 64;
  const int quad = lane >> 4, l16 = lane & 15;

  DECL_ACC

  const int qa = tid, qb = tid + 256;
  const int ra = qa >> 2, ca = (qa & 3) * 8;
  const int rb = qb >> 2, cb = (qb & 3) * 8;

  for (int k0 = 0; k0 < 1024; k0 += 32) {
    async16(X + (size_t)(m0 + ra) * 1024 + k0 + ca, lA + qa * 8);
    async16(X + (size_t)(m0 + rb) * 1024 + k0 + cb, lA + qb * 8);
    async16(W + (size_t)(n0 + ra) * 1024 + k0 + ca, lB + qa * 8);
    async16(W + (size_t)(n0 + rb) * 1024 + k0 + cb, lB + qb * 8);
    __syncthreads();
    KLOOP_FRAGS_MFMA
    __syncthreads();
  }

  const int h = (n0 + wn) >> 6;
  const int mbase = m0 + wm;
  const int b = mbase >> 11, s0 = mbase & 2047;
  bf16* myT = lT[w];

  if (z <= 1) {
    const float scl = (z == 0) ? 0.125f : 1.0f;
    const float invf0 = expf(-0.28782313662425572f * (float)l16);   // ln(1e4)/32
    const float invf1 = expf(-0.28782313662425572f * (float)(16 + l16));
    ROPE_I(0, a00, a01, a02, a03)
    ROPE_I(1, a10, a11, a12, a13)
    ROPE_I(2, a20, a21, a22, a23)
    ROPE_I(3, a30, a31, a32, a33)
    asm volatile("s_waitcnt lgkmcnt(0)" ::: "memory");
    bf16* dst = (z == 0) ? Q : Ko;
    const int rr = lane >> 3, cc = lane & 7;
#pragma unroll
    for (int it = 0; it < 8; it++) {
      int mloc = it * 8 + rr;
      bf16x8 v = *(const bf16x8*)(myT + mloc * LTS + cc * 8);
      *(bf16x8*)(dst + (((size_t)b * NH_ + h) * S_ + s0 + mloc) * HD_ + cc * 8) = v;
    }
  } else {
    VW(0, 0, a00) VW(0, 1, a01) VW(0, 2, a02) VW(0, 3, a03)
    VW(1, 0, a10) VW(1, 1, a11) VW(1, 2, a12) VW(1, 3, a13)
    VW(2, 0, a20) VW(2, 1, a21) VW(2, 2, a22) VW(2, 3, a23)
    VW(3, 0, a30) VW(3, 1, a31) VW(3, 2, a32) VW(3, 3, a33)
    asm volatile("s_waitcnt lgkmcnt(0)" ::: "memory");
    const int rr = lane >> 3, cc = lane & 7;
#pragma unroll
    for (int it = 0; it < 8; it++) {
      int d = it * 8 + rr;
      bf16x8 v = *(const bf16x8*)(myT + d * LTS + cc * 8);
      *(bf16x8*)(Vt + (((size_t)b * NH_ + h) * HD_ + d) * S_ + s0 + cc * 8) = v;
    }
  }
}

// ---------------- flash attention, S^T formulation.
// S^T = K·Q^T so each lane owns 16 score elements of ONE q-row (n = l16):
// softmax reductions are in-lane + 2 shfls; P written vectorized+swizzled.
__global__ void attn_kernel(
    const bf16* __restrict__ Q, const bf16* __restrict__ K,
    const bf16* __restrict__ Vt, const float* __restrict__ mask,
    bf16* __restrict__ ctx) {
  const int b = blockIdx.y >> 4, h = blockIdx.y & 15;
  const int q0 = blockIdx.x * 64;
  __shared__ __align__(16) bf16 lQ[64 * 64];    // Q tile; reused as O-transpose tile
  __shared__ __align__(16) bf16 lK[64 * 64];
  __shared__ __align__(16) bf16 lV[64 * 64];    // V^T tile: [d][k]
  __shared__ __align__(16) bf16 lP[4][16 * 64]; // per-wave P: [n(16)][k(64)], XOR-swizzled
  const int tid = threadIdx.x;
  const int lane = tid & 63, w = tid >> 6;
  const int quad = lane >> 4, l16 = lane & 15;

  const size_t headoff = ((size_t)b * NH_ + h) * S_ * HD_;
  {
    const bf16* src = Q + headoff + (size_t)q0 * HD_;
    async16(src + tid * 8, lQ + tid * 8);
    async16(src + (tid + 256) * 8, lQ + (tid + 256) * 8);
  }

  f32x4 o0 = {}, o1 = {}, o2 = {}, o3 = {};
  float m_run = -1e30f, l_run = 0.f;
  const float* mrow = mask + ((size_t)b * S_ + q0 + w * 16 + l16) * S_;  // this lane's q-row
  const int swz = 8 * (l16 & 7);
  bf16* myP = lP[w];

  for (int kt = 0; kt < 32; kt++) {
    const int k0 = kt * 64;
    const bf16* ksrc = K + headoff + (size_t)k0 * HD_;
    async16(ksrc + tid * 8, lK + tid * 8);
    async16(ksrc + (tid + 256) * 8, lK + (tid + 256) * 8);
    {
      const bf16* vbase = Vt + headoff;
      async16(vbase + (size_t)(tid >> 3) * S_ + k0 + (tid & 7) * 8, lV + tid * 8);
      async16(vbase + (size_t)((tid + 256) >> 3) * S_ + k0 + ((tid + 256) & 7) * 8,
              lV + (tid + 256) * 8);
    }
    __syncthreads();

    // S^T: A = K-frags (rows kcol), B = Q-frag. s_j C-layout:
    // row = kcol-local = quad*4+r, col = q-row-local = l16.
    f32x4 s0 = {}, s1 = {}, s2 = {}, s3 = {};
    {
      bf16x8 bq = *(const bf16x8*)(lQ + (w * 16 + l16) * 64 + quad * 8);
      bf16x8 k0f = *(const bf16x8*)(lK + (0 * 16 + l16) * 64 + quad * 8);
      bf16x8 k1f = *(const bf16x8*)(lK + (1 * 16 + l16) * 64 + quad * 8);
      bf16x8 k2f = *(const bf16x8*)(lK + (2 * 16 + l16) * 64 + quad * 8);
      bf16x8 k3f = *(const bf16x8*)(lK + (3 * 16 + l16) * 64 + quad * 8);
      MM16(k0f, bq, s0); MM16(k1f, bq, s1); MM16(k2f, bq, s2); MM16(k3f, bq, s3);
    }
    {
      bf16x8 bq = *(const bf16x8*)(lQ + (w * 16 + l16) * 64 + 32 + quad * 8);
      bf16x8 k0f = *(const bf16x8*)(lK + (0 * 16 + l16) * 64 + 32 + quad * 8);
      bf16x8 k1f = *(const bf16x8*)(lK + (1 * 16 + l16) * 64 + 32 + quad * 8);
      bf16x8 k2f = *(const bf16x8*)(lK + (2 * 16 + l16) * 64 + 32 + quad * 8);
      bf16x8 k3f = *(const bf16x8*)(lK + (3 * 16 + l16) * 64 + 32 + quad * 8);
      MM16(k0f, bq, s0); MM16(k1f, bq, s1); MM16(k2f, bq, s2); MM16(k3f, bq, s3);
    }

    // mask (vectorized) + online softmax, all in-lane for row n = l16
    const float4* m4 = (const float4*)(mrow + k0);
    float4 f0 = m4[quad], f1 = m4[4 + quad], f2 = m4[8 + quad], f3 = m4[12 + quad];
    float v00 = s0[0] + f0.x, v01 = s0[1] + f0.y, v02 = s0[2] + f0.z, v03 = s0[3] + f0.w;
    float v10 = s1[0] + f1.x, v11 = s1[1] + f1.y, v12 = s1[2] + f1.z, v13 = s1[3] + f1.w;
    float v20 = s2[0] + f2.x, v21 = s2[1] + f2.y, v22 = s2[2] + f2.z, v23 = s2[3] + f2.w;
    float v30 = s3[0] + f3.x, v31 = s3[1] + f3.y, v32 = s3[2] + f3.z, v33 = s3[3] + f3.w;

    float mx = fmaxf(fmaxf(fmaxf(v00, v01), fmaxf(v02, v03)),
                     fmaxf(fmaxf(v10, v11), fmaxf(v12, v13)));
    mx = fmaxf(mx, fmaxf(fmaxf(fmaxf(v20, v21), fmaxf(v22, v23)),
                         fmaxf(fmaxf(v30, v31), fmaxf(v32, v33))));
    mx = fmaxf(mx, __shfl_xor(mx, 16));
    mx = fmaxf(mx, __shfl_xor(mx, 32));
    const float mnew = fmaxf(m_run, mx);
    const float alpha = expf(m_run - mnew);
    m_run = mnew;

    float p00 = expf(v00 - mnew), p01 = expf(v01 - mnew), p02 = expf(v02 - mnew), p03 = expf(v03 - mnew);
    float p10 = expf(v10 - mnew), p11 = expf(v11 - mnew), p12 = expf(v12 - mnew), p13 = expf(v13 - mnew);
    float p20 = expf(v20 - mnew), p21 = expf(v21 - mnew), p22 = expf(v22 - mnew), p23 = expf(v23 - mnew);
    float p30 = expf(v30 - mnew), p31 = expf(v31 - mnew), p32 = expf(v32 - mnew), p33 = expf(v33 - mnew);

    {  // vectorized swizzled P stores: element (n=l16, k) at n*64 + (k ^ swz)
      bf16x4 pk;
      pk[0] = (bf16)p00; pk[1] = (bf16)p01; pk[2] = (bf16)p02; pk[3] = (bf16)p03;
      *(bf16x4*)(myP + l16 * 64 + ((0 * 16 + quad * 4) ^ swz)) = pk;
      pk[0] = (bf16)p10; pk[1] = (bf16)p11; pk[2] = (bf16)p12; pk[3] = (bf16)p13;
      *(bf16x4*)(myP + l16 * 64 + ((1 * 16 + quad * 4) ^ swz)) = pk;
      pk[0] = (bf16)p20; pk[1] = (bf16)p21; pk[2] = (bf16)p22; pk[3] = (bf16)p23;
      *(bf16x4*)(myP + l16 * 64 + ((2 * 16 + quad * 4) ^ swz)) = pk;
      pk[0] = (bf16)p30; pk[1] = (bf16)p31; pk[2] = (bf16)p32; pk[3] = (bf16)p33;
      *(bf16x4*)(myP + l16 * 64 + ((3 * 16 + quad * 4) ^ swz)) = pk;
    }

    float ps = (((p00 + p01) + (p02 + p03)) + ((p10 + p11) + (p12 + p13)))
             + (((p20 + p21) + (p22 + p23)) + ((p30 + p31) + (p32 + p33)));
    ps += __shfl_xor(ps, 16);
    ps += __shfl_xor(ps, 32);
    l_run = l_run * alpha + ps;

    // broadcast alpha for rows quad*4+r (held by lanes 0..15) and rescale O
    f32x4 av;
    av[0] = __shfl(alpha, quad * 4 + 0);
    av[1] = __shfl(alpha, quad * 4 + 1);
    av[2] = __shfl(alpha, quad * 4 + 2);
    av[3] = __shfl(alpha, quad * 4 + 3);
    o0 *= av; o1 *= av; o2 *= av; o3 *= av;

    // O += P V : A = P-frag (swizzled read), B = V^T frag. o_j: row=m, col=d-block j.
    {
      bf16x8 ap = *(const bf16x8*)(myP + l16 * 64 + ((quad * 8) ^ swz));
      bf16x8 b0 = *(const bf16x8*)(lV + (0 * 16 + l16) * 64 + quad * 8);
      bf16x8 b1 = *(const bf16x8*)(lV + (1 * 16 + l16) * 64 + quad * 8);
      bf16x8 b2 = *(const bf16x8*)(lV + (2 * 16 + l16) * 64 + quad * 8);
      bf16x8 b3 = *(const bf16x8*)(lV + (3 * 16 + l16) * 64 + quad * 8);
      MM16(ap, b0, o0); MM16(ap, b1, o1); MM16(ap, b2, o2); MM16(ap, b3, o3);
    }
    {
      bf16x8 ap = *(const bf16x8*)(myP + l16 * 64 + ((32 + quad * 8) ^ swz));
      bf16x8 b0 = *(const bf16x8*)(lV + (0 * 16 + l16) * 64 + 32 + quad * 8);
      bf16x8 b1 = *(const bf16x8*)(lV + (1 * 16 + l16) * 64 + 32 + quad * 8);
      bf16x8 b2 = *(const bf16x8*)(lV + (2 * 16 + l16) * 64 + 32 + quad * 8);
      bf16x8 b3 = *(const bf16x8*)(lV + (3 * 16 + l16) * 64 + 32 + quad * 8);
      MM16(ap, b0, o0); MM16(ap, b1, o1); MM16(ap, b2, o2); MM16(ap, b3, o3);
    }
    __syncthreads();
  }

  // epilogue: 1/l for rows quad*4+r, normalize, coalesced store via lQ
  f32x4 lv;
  lv[0] = __shfl(l_run, quad * 4 + 0);
  lv[1] = __shfl(l_run, quad * 4 + 1);
  lv[2] = __shfl(l_run, quad * 4 + 2);
  lv[3] = __shfl(l_run, quad * 4 + 3);
#pragma unroll
  for (int r = 0; r < 4; r++) {
    const float invl = 1.0f / lv[r];
    const int sloc = w * 16 + quad * 4 + r;
    lQ[sloc * 64 + l16]      = (bf16)(o0[r] * invl);
    lQ[sloc * 64 + 16 + l16] = (bf16)(o1[r] * invl);
    lQ[sloc * 64 + 32 + l16] = (bf16)(o2[r] * invl);
    lQ[sloc * 64 + 48 + l16] = (bf16)(o3[r] * invl);
  }
  __syncthreads();
  {
    const int rr = tid >> 3, cc = tid & 7;
#pragma unroll
    for (int it = 0; it < 2; it++) {
      int sloc = it * 32 + rr;
      bf16x8 v = *(const bf16x8*)(lQ + sloc * 64 + cc * 8);
      *(bf16x8*)(ctx + ((size_t)b * S_ + q0 + sloc) * HID_ + h * HD_ + cc * 8) = v;
    }
  }
}

#define PW(i, j, C) { \
  float* po = out + (size_t)(m0 + wm + (i) * 16 + quad * 4) * 1024 + n0 + wn + (j) * 16 + l16; \
  po[0] = C[0]; po[1024] = C[1]; po[2048] = C[2]; po[3072] = C[3]; }

// ---------------- output projection: out(fp32) = ctx @ Wo^T
__global__ void proj_gemm(
    const bf16* __restrict__ A, const bf16* __restrict__ Wo, float* __restrict__ out) {
  const int m0 = blockIdx.y * 128;
  const int n0 = blockIdx.x * 128;
  __shared__ __align__(16) bf16 lA[128 * 32];
  __shared__ __align__(16) bf16 lB[128 * 32];
  const int tid = threadIdx.x;
  const int lane = tid & 63, w = tid >> 6;
  const int wm = (w >> 1) * 64, wn = (w & 1) * 64;
  const int quad = lane >> 4, l16 = lane & 15;

  DECL_ACC
  const int qa = tid, qb = tid + 256;
  const int ra = qa >> 2, ca = (qa & 3) * 8;
  const int rb = qb >> 2, cb = (qb & 3) * 8;

  for (int k0 = 0; k0 < 1024; k0 += 32) {
    async16(A + (size_t)(m0 + ra) * 1024 + k0 + ca, lA + qa * 8);
    async16(A + (size_t)(m0 + rb) * 1024 + k0 + cb, lA + qb * 8);
    async16(Wo + (size_t)(n0 + ra) * 1024 + k0 + ca, lB + qa * 8);
    async16(Wo + (size_t)(n0 + rb) * 1024 + k0 + cb, lB + qb * 8);
    __syncthreads();
    KLOOP_FRAGS_MFMA
    __syncthreads();
  }
  PW(0, 0, a00) PW(0, 1, a01) PW(0, 2, a02) PW(0, 3, a03)
  PW(1, 0, a10) PW(1, 1, a11) PW(1, 2, a12) PW(1, 3, a13)
  PW(2, 0, a20) PW(2, 1, a21) PW(2, 2, a22) PW(2, 3, a23)
  PW(3, 0, a30) PW(3, 1, a31) PW(3, 2, a32) PW(3, 3, a33)
}

__global__ void sentinel_kernel(float* out, int n, float val) {
  int i = blockIdx.x * 256 + threadIdx.x;
  if (i < n) out[i] = val;
}

extern "C" void kernel_launch(void* const* d_in, const int* in_sizes, int n_in,
                              void* d_out, int out_size, void* d_ws, size_t ws_size,
                              hipStream_t stream) {
  const float* X    = (const float*)d_in[0];
  const float* mask = (const float*)d_in[1];
  const int*   pos  = (const int*)d_in[2];
  const float* Wq   = (const float*)d_in[3];
  const float* Wk   = (const float*)d_in[4];
  const float* Wv   = (const float*)d_in[5];
  const float* Wo   = (const float*)d_in[6];
  float* out = (float*)d_out;

  char* ws = (char*)d_ws;
  const size_t SZ = (size_t)B_ * NH_ * S_ * HD_ * sizeof(bf16);  // 16 MiB
  if (ws_size < 3 * SZ) {
    sentinel_kernel<<<(out_size + 255) / 256, 256, 0, stream>>>(
        out, out_size, (float)(ws_size >> 20));
    return;
  }

  // ws layout (48 MiB): [0,16M) Xb then ctx; [16M,32M) Q; [32M,48M) Vt then Wob.
  bf16* Xb  = (bf16*)(ws);
  bf16* ctx = (bf16*)(ws);
  bf16* Q   = (bf16*)(ws + SZ);
  bf16* Vt  = (bf16*)(ws + 2 * SZ);
  bf16* Wob = (bf16*)(ws + 2 * SZ);
  // d_out hosts bf16 K [0,16M) and Wq/Wk/Wv bf16 [16M,22M) until proj overwrites.
  bf16* Kb  = (bf16*)d_out;
  bf16* Wqb = (bf16*)((char*)d_out + SZ);
  bf16* Wkb = Wqb + 1024 * 1024;
  bf16* Wvb = Wkb + 1024 * 1024;

  const int nX4 = (B_ * S_ * HID_) / 4;
  const int nW4 = (HID_ * HID_) / 4;
  cvt_kernel<<<(nX4 + 255) / 256, 256, 0, stream>>>(X, Xb, nX4);
  cvt_kernel<<<(nW4 + 255) / 256, 256, 0, stream>>>(Wq, Wqb, nW4);
  cvt_kernel<<<(nW4 + 255) / 256, 256, 0, stream>>>(Wk, Wkb, nW4);
  cvt_kernel<<<(nW4 + 255) / 256, 256, 0, stream>>>(Wv, Wvb, nW4);

  qkv_gemm<<<dim3(8, 64, 3), 256, 0, stream>>>(Xb, Wqb, Wkb, Wvb, pos, Q, Kb, Vt);
  attn_kernel<<<dim3(32, 64), 256, 0, stream>>>(Q, Kb, Vt, mask, ctx);

  cvt_kernel<<<(nW4 + 255) / 256, 256, 0, stream>>>(Wo, Wob, nW4);
  proj_gemm<<<dim3(8, 64), 256, 0, stream>>>(ctx, Wob, out);
}

// Round 8
// 428.994 us; speedup vs baseline: 3.3350x; 1.1618x over previous
//
#include <hip/hip_runtime.h>
#include <hip/hip_bf16.h>
#include <math.h>

typedef __bf16 bf16;
typedef bf16 bf16x4 __attribute__((ext_vector_type(4)));
typedef bf16 bf16x8 __attribute__((ext_vector_type(8)));
typedef float f32x4 __attribute__((ext_vector_type(4)));

#define B_ 4
#define S_ 2048
#define HID_ 1024
#define NH_ 16
#define HD_ 64
#define LTS 72   // padded LDS tile stride

// async global->LDS, 16B per lane. LDS dest must be wave-uniform base + lane*16.
__device__ __forceinline__ void async16(const bf16* g, bf16* l) {
  __builtin_amdgcn_global_load_lds(
      (const __attribute__((address_space(1))) void*)g,
      (__attribute__((address_space(3))) void*)l, 16, 0, 0);
}

#define MM16(A, B, C) C = __builtin_amdgcn_mfma_f32_16x16x32_bf16(A, B, C, 0, 0, 0)

// ---------------- fp32 -> bf16 convert
__global__ void cvt_kernel(const float* __restrict__ src, bf16* __restrict__ dst, int n4) {
  int i = blockIdx.x * 256 + threadIdx.x;
  if (i < n4) {
    float4 v = ((const float4*)src)[i];
    bf16x4 o;
    o[0] = (bf16)v.x; o[1] = (bf16)v.y; o[2] = (bf16)v.z; o[3] = (bf16)v.w;
    ((bf16x4*)dst)[i] = o;
  }
}

// K-loop body shared by qkv/proj: named accs, frag loads, 16 MFMAs.
#define DECL_ACC \
  f32x4 a00 = {}, a01 = {}, a02 = {}, a03 = {}; \
  f32x4 a10 = {}, a11 = {}, a12 = {}, a13 = {}; \
  f32x4 a20 = {}, a21 = {}, a22 = {}, a23 = {}; \
  f32x4 a30 = {}, a31 = {}, a32 = {}, a33 = {};

#define KLOOP_FRAGS_MFMA \
    bf16x8 af0 = *(const bf16x8*)(lA + (wm + 0 * 16 + l16) * 32 + quad * 8); \
    bf16x8 af1 = *(const bf16x8*)(lA + (wm + 1 * 16 + l16) * 32 + quad * 8); \
    bf16x8 af2 = *(const bf16x8*)(lA + (wm + 2 * 16 + l16) * 32 + quad * 8); \
    bf16x8 af3 = *(const bf16x8*)(lA + (wm + 3 * 16 + l16) * 32 + quad * 8); \
    bf16x8 bg0 = *(const bf16x8*)(lB + (wn + 0 * 16 + l16) * 32 + quad * 8); \
    bf16x8 bg1 = *(const bf16x8*)(lB + (wn + 1 * 16 + l16) * 32 + quad * 8); \
    bf16x8 bg2 = *(const bf16x8*)(lB + (wn + 2 * 16 + l16) * 32 + quad * 8); \
    bf16x8 bg3 = *(const bf16x8*)(lB + (wn + 3 * 16 + l16) * 32 + quad * 8); \
    MM16(af0, bg0, a00); MM16(af0, bg1, a01); MM16(af0, bg2, a02); MM16(af0, bg3, a03); \
    MM16(af1, bg0, a10); MM16(af1, bg1, a11); MM16(af1, bg2, a12); MM16(af1, bg3, a13); \
    MM16(af2, bg0, a20); MM16(af2, bg1, a21); MM16(af2, bg2, a22); MM16(af2, bg3, a23); \
    MM16(af3, bg0, a30); MM16(af3, bg1, a31); MM16(af3, bg2, a32); MM16(af3, bg3, a33);

// RoPE epilogue per (i, r) — fast trig (range ~2048 rad: __cosf err ~1e-4 << bf16 eps)
#define ROPE_R(i, r, C0, C1, C2, C3) { \
  const int mloc = (i) * 16 + quad * 4 + (r); \
  const float p = (float)pos[mbase + mloc]; \
  const float aa0 = p * invf0, aa1 = p * invf1; \
  const float c0 = __cosf(aa0), sn0 = __sinf(aa0); \
  const float c1 = __cosf(aa1), sn1 = __sinf(aa1); \
  myT[mloc * LTS + l16]      = (bf16)((C0[r] * c0 - C2[r] * sn0) * scl); \
  myT[mloc * LTS + 32 + l16] = (bf16)((C2[r] * c0 + C0[r] * sn0) * scl); \
  myT[mloc * LTS + 16 + l16] = (bf16)((C1[r] * c1 - C3[r] * sn1) * scl); \
  myT[mloc * LTS + 48 + l16] = (bf16)((C3[r] * c1 + C1[r] * sn1) * scl); }
#define ROPE_I(i, C0, C1, C2, C3) \
  ROPE_R(i, 0, C0, C1, C2, C3) ROPE_R(i, 1, C0, C1, C2, C3) \
  ROPE_R(i, 2, C0, C1, C2, C3) ROPE_R(i, 3, C0, C1, C2, C3)

#define VW(i, j, C) { \
  bf16x4 o; o[0] = (bf16)C[0]; o[1] = (bf16)C[1]; o[2] = (bf16)C[2]; o[3] = (bf16)C[3]; \
  *(bf16x4*)(myT + ((j) * 16 + l16) * LTS + (i) * 16 + quad * 4) = o; }

// ---------------- QKV GEMM: Y = Xb @ Wb^T, fused RoPE.
__global__ void qkv_gemm(
    const bf16* __restrict__ X, const bf16* __restrict__ Wq,
    const bf16* __restrict__ Wk, const bf16* __restrict__ Wv,
    const int* __restrict__ pos,
    bf16* __restrict__ Q, bf16* __restrict__ Ko, bf16* __restrict__ Vt) {
  const int z = blockIdx.z;
  const bf16* W = (z == 0) ? Wq : (z == 1) ? Wk : Wv;
  const int m0 = blockIdx.y * 128;
  const int n0 = blockIdx.x * 128;
  __shared__ __align__(16) bf16 lA[128 * 32];
  __shared__ __align__(16) bf16 lB[128 * 32];
  __shared__ __align__(16) bf16 lT[4][64 * LTS];
  const int tid = threadIdx.x;
  const int lane = tid & 63, w = tid >> 6;
  const int wm = (w >> 1) * 64, wn = (w & 1) * 64;
  const int quad = lane >> 4, l16 = lane & 15;

  DECL_ACC

  const int qa = tid, qb = tid + 256;
  const int ra = qa >> 2, ca = (qa & 3) * 8;
  const int rb = qb >> 2, cb = (qb & 3) * 8;

  for (int k0 = 0; k0 < 1024; k0 += 32) {
    async16(X + (size_t)(m0 + ra) * 1024 + k0 + ca, lA + qa * 8);
    async16(X + (size_t)(m0 + rb) * 1024 + k0 + cb, lA + qb * 8);
    async16(W + (size_t)(n0 + ra) * 1024 + k0 + ca, lB + qa * 8);
    async16(W + (size_t)(n0 + rb) * 1024 + k0 + cb, lB + qb * 8);
    __syncthreads();
    KLOOP_FRAGS_MFMA
    __syncthreads();
  }

  const int h = (n0 + wn) >> 6;
  const int mbase = m0 + wm;
  const int b = mbase >> 11, s0 = mbase & 2047;
  bf16* myT = lT[w];

  if (z <= 1) {
    const float scl = (z == 0) ? 0.125f : 1.0f;
    const float invf0 = __expf(-0.28782313662425572f * (float)l16);   // ln(1e4)/32
    const float invf1 = __expf(-0.28782313662425572f * (float)(16 + l16));
    ROPE_I(0, a00, a01, a02, a03)
    ROPE_I(1, a10, a11, a12, a13)
    ROPE_I(2, a20, a21, a22, a23)
    ROPE_I(3, a30, a31, a32, a33)
    asm volatile("s_waitcnt lgkmcnt(0)" ::: "memory");
    bf16* dst = (z == 0) ? Q : Ko;
    const int rr = lane >> 3, cc = lane & 7;
#pragma unroll
    for (int it = 0; it < 8; it++) {
      int mloc = it * 8 + rr;
      bf16x8 v = *(const bf16x8*)(myT + mloc * LTS + cc * 8);
      *(bf16x8*)(dst + (((size_t)b * NH_ + h) * S_ + s0 + mloc) * HD_ + cc * 8) = v;
    }
  } else {
    VW(0, 0, a00) VW(0, 1, a01) VW(0, 2, a02) VW(0, 3, a03)
    VW(1, 0, a10) VW(1, 1, a11) VW(1, 2, a12) VW(1, 3, a13)
    VW(2, 0, a20) VW(2, 1, a21) VW(2, 2, a22) VW(2, 3, a23)
    VW(3, 0, a30) VW(3, 1, a31) VW(3, 2, a32) VW(3, 3, a33)
    asm volatile("s_waitcnt lgkmcnt(0)" ::: "memory");
    const int rr = lane >> 3, cc = lane & 7;
#pragma unroll
    for (int it = 0; it < 8; it++) {
      int d = it * 8 + rr;
      bf16x8 v = *(const bf16x8*)(myT + d * LTS + cc * 8);
      *(bf16x8*)(Vt + (((size_t)b * NH_ + h) * HD_ + d) * S_ + s0 + cc * 8) = v;
    }
  }
}

// ---------------- flash attention, S^T formulation, bank-balanced LDS tiles.
// All 64-elem-row tiles (lQ/lK/lV) store chunk c of row r at physical chunk
// c ^ (r&7): staging applies the XOR at the global SOURCE address (LDS dest
// stays lane-contiguous as global_load_lds requires); reads apply it too.
__global__ void attn_kernel(
    const bf16* __restrict__ Q, const bf16* __restrict__ K,
    const bf16* __restrict__ Vt, const float* __restrict__ mask,
    bf16* __restrict__ ctx) {
  const int b = blockIdx.y >> 4, h = blockIdx.y & 15;
  const int q0 = blockIdx.x * 64;
  __shared__ __align__(16) bf16 lQ[64 * 64];    // Q tile; reused as O-transpose tile
  __shared__ __align__(16) bf16 lK[64 * 64];
  __shared__ __align__(16) bf16 lV[64 * 64];    // V^T tile: [d][k]
  __shared__ __align__(16) bf16 lP[4][16 * 64]; // per-wave P: [n(16)][k(64)], swizzled
  const int tid = threadIdx.x;
  const int lane = tid & 63, w = tid >> 6;
  const int quad = lane >> 4, l16 = lane & 15;

  // staging geometry: first call rows 0..31, second rows 32..63 (same row&7)
  const int sr = tid >> 3;
  const int scs = (tid & 7) ^ (sr & 7);   // swizzled source chunk

  const size_t headoff = ((size_t)b * NH_ + h) * S_ * HD_;
  {
    const bf16* src = Q + headoff + (size_t)q0 * HD_;
    async16(src + sr * 64 + scs * 8, lQ + tid * 8);
    async16(src + (sr + 32) * 64 + scs * 8, lQ + (tid + 256) * 8);
  }

  f32x4 o0 = {}, o1 = {}, o2 = {}, o3 = {};
  float m_run = -1e30f, l_run = 0.f;
  const float* mrow = mask + ((size_t)b * S_ + q0 + w * 16 + l16) * S_;  // lane's q-row
  const int sw = l16 & 7;
  const int pq  = (quad ^ sw) * 8;         // physical chunk offset, k-half 0
  const int pq2 = ((quad + 4) ^ sw) * 8;   // k-half 1
  bf16* myP = lP[w];

  for (int kt = 0; kt < 32; kt++) {
    const int k0 = kt * 64;
    const bf16* ksrc = K + headoff + (size_t)k0 * HD_;
    async16(ksrc + sr * 64 + scs * 8, lK + tid * 8);
    async16(ksrc + (sr + 32) * 64 + scs * 8, lK + (tid + 256) * 8);
    {
      const bf16* vbase = Vt + headoff + k0;
      async16(vbase + (size_t)sr * S_ + scs * 8, lV + tid * 8);
      async16(vbase + (size_t)(sr + 32) * S_ + scs * 8, lV + (tid + 256) * 8);
    }
    __syncthreads();

    // S^T: A = K-frags (rows = k-cols), B = Q-frag. C-layout:
    // row = quad*4+r (k-col-local), col = l16 (q-row-local).
    f32x4 s0 = {}, s1 = {}, s2 = {}, s3 = {};
    {
      bf16x8 bq = *(const bf16x8*)(lQ + (w * 16 + l16) * 64 + pq);
      bf16x8 k0f = *(const bf16x8*)(lK + (0 * 16 + l16) * 64 + pq);
      bf16x8 k1f = *(const bf16x8*)(lK + (1 * 16 + l16) * 64 + pq);
      bf16x8 k2f = *(const bf16x8*)(lK + (2 * 16 + l16) * 64 + pq);
      bf16x8 k3f = *(const bf16x8*)(lK + (3 * 16 + l16) * 64 + pq);
      MM16(k0f, bq, s0); MM16(k1f, bq, s1); MM16(k2f, bq, s2); MM16(k3f, bq, s3);
    }
    {
      bf16x8 bq = *(const bf16x8*)(lQ + (w * 16 + l16) * 64 + pq2);
      bf16x8 k0f = *(const bf16x8*)(lK + (0 * 16 + l16) * 64 + pq2);
      bf16x8 k1f = *(const bf16x8*)(lK + (1 * 16 + l16) * 64 + pq2);
      bf16x8 k2f = *(const bf16x8*)(lK + (2 * 16 + l16) * 64 + pq2);
      bf16x8 k3f = *(const bf16x8*)(lK + (3 * 16 + l16) * 64 + pq2);
      MM16(k0f, bq, s0); MM16(k1f, bq, s1); MM16(k2f, bq, s2); MM16(k3f, bq, s3);
    }

    // mask (vectorized) + online softmax, in-lane for q-row l16
    const float4* m4 = (const float4*)(mrow + k0);
    float4 f0 = m4[quad], f1 = m4[4 + quad], f2 = m4[8 + quad], f3 = m4[12 + quad];
    float v00 = s0[0] + f0.x, v01 = s0[1] + f0.y, v02 = s0[2] + f0.z, v03 = s0[3] + f0.w;
    float v10 = s1[0] + f1.x, v11 = s1[1] + f1.y, v12 = s1[2] + f1.z, v13 = s1[3] + f1.w;
    float v20 = s2[0] + f2.x, v21 = s2[1] + f2.y, v22 = s2[2] + f2.z, v23 = s2[3] + f2.w;
    float v30 = s3[0] + f3.x, v31 = s3[1] + f3.y, v32 = s3[2] + f3.z, v33 = s3[3] + f3.w;

    float mx = fmaxf(fmaxf(fmaxf(v00, v01), fmaxf(v02, v03)),
                     fmaxf(fmaxf(v10, v11), fmaxf(v12, v13)));
    mx = fmaxf(mx, fmaxf(fmaxf(fmaxf(v20, v21), fmaxf(v22, v23)),
                         fmaxf(fmaxf(v30, v31), fmaxf(v32, v33))));
    mx = fmaxf(mx, __shfl_xor(mx, 16));
    mx = fmaxf(mx, __shfl_xor(mx, 32));
    const float mnew = fmaxf(m_run, mx);
    const float alpha = __expf(m_run - mnew);
    m_run = mnew;

    float p00 = __expf(v00 - mnew), p01 = __expf(v01 - mnew), p02 = __expf(v02 - mnew), p03 = __expf(v03 - mnew);
    float p10 = __expf(v10 - mnew), p11 = __expf(v11 - mnew), p12 = __expf(v12 - mnew), p13 = __expf(v13 - mnew);
    float p20 = __expf(v20 - mnew), p21 = __expf(v21 - mnew), p22 = __expf(v22 - mnew), p23 = __expf(v23 - mnew);
    float p30 = __expf(v30 - mnew), p31 = __expf(v31 - mnew), p32 = __expf(v32 - mnew), p33 = __expf(v33 - mnew);

    {  // swizzled P stores: element (n=l16, k) at n*64 + (k ^ 8*sw)
      const int swz = 8 * sw;
      bf16x4 pk;
      pk[0] = (bf16)p00; pk[1] = (bf16)p01; pk[2] = (bf16)p02; pk[3] = (bf16)p03;
      *(bf16x4*)(myP + l16 * 64 + ((0 * 16 + quad * 4) ^ swz)) = pk;
      pk[0] = (bf16)p10; pk[1] = (bf16)p11; pk[2] = (bf16)p12; pk[3] = (bf16)p13;
      *(bf16x4*)(myP + l16 * 64 + ((1 * 16 + quad * 4) ^ swz)) = pk;
      pk[0] = (bf16)p20; pk[1] = (bf16)p21; pk[2] = (bf16)p22; pk[3] = (bf16)p23;
      *(bf16x4*)(myP + l16 * 64 + ((2 * 16 + quad * 4) ^ swz)) = pk;
      pk[0] = (bf16)p30; pk[1] = (bf16)p31; pk[2] = (bf16)p32; pk[3] = (bf16)p33;
      *(bf16x4*)(myP + l16 * 64 + ((3 * 16 + quad * 4) ^ swz)) = pk;
    }

    float ps = (((p00 + p01) + (p02 + p03)) + ((p10 + p11) + (p12 + p13)))
             + (((p20 + p21) + (p22 + p23)) + ((p30 + p31) + (p32 + p33)));
    ps += __shfl_xor(ps, 16);
    ps += __shfl_xor(ps, 32);
    l_run = l_run * alpha + ps;

    // broadcast alpha for rows quad*4+r and rescale O
    f32x4 av;
    av[0] = __shfl(alpha, quad * 4 + 0);
    av[1] = __shfl(alpha, quad * 4 + 1);
    av[2] = __shfl(alpha, quad * 4 + 2);
    av[3] = __shfl(alpha, quad * 4 + 3);
    o0 *= av; o1 *= av; o2 *= av; o3 *= av;

    // O += P V : A = P-frag (swizzled), B = V^T frag (swizzled)
    {
      bf16x8 ap = *(const bf16x8*)(myP + l16 * 64 + pq);
      bf16x8 b0 = *(const bf16x8*)(lV + (0 * 16 + l16) * 64 + pq);
      bf16x8 b1 = *(const bf16x8*)(lV + (1 * 16 + l16) * 64 + pq);
      bf16x8 b2 = *(const bf16x8*)(lV + (2 * 16 + l16) * 64 + pq);
      bf16x8 b3 = *(const bf16x8*)(lV + (3 * 16 + l16) * 64 + pq);
      MM16(ap, b0, o0); MM16(ap, b1, o1); MM16(ap, b2, o2); MM16(ap, b3, o3);
    }
    {
      bf16x8 ap = *(const bf16x8*)(myP + l16 * 64 + pq2);
      bf16x8 b0 = *(const bf16x8*)(lV + (0 * 16 + l16) * 64 + pq2);
      bf16x8 b1 = *(const bf16x8*)(lV + (1 * 16 + l16) * 64 + pq2);
      bf16x8 b2 = *(const bf16x8*)(lV + (2 * 16 + l16) * 64 + pq2);
      bf16x8 b3 = *(const bf16x8*)(lV + (3 * 16 + l16) * 64 + pq2);
      MM16(ap, b0, o0); MM16(ap, b1, o1); MM16(ap, b2, o2); MM16(ap, b3, o3);
    }
    __syncthreads();
  }

  // epilogue: 1/l for rows quad*4+r, normalize, coalesced store via lQ
  f32x4 lv;
  lv[0] = __shfl(l_run, quad * 4 + 0);
  lv[1] = __shfl(l_run, quad * 4 + 1);
  lv[2] = __shfl(l_run, quad * 4 + 2);
  lv[3] = __shfl(l_run, quad * 4 + 3);
#pragma unroll
  for (int r = 0; r < 4; r++) {
    const float invl = 1.0f / lv[r];
    const int sloc = w * 16 + quad * 4 + r;
    lQ[sloc * 64 + l16]      = (bf16)(o0[r] * invl);
    lQ[sloc * 64 + 16 + l16] = (bf16)(o1[r] * invl);
    lQ[sloc * 64 + 32 + l16] = (bf16)(o2[r] * invl);
    lQ[sloc * 64 + 48 + l16] = (bf16)(o3[r] * invl);
  }
  __syncthreads();
  {
    const int rr = tid >> 3, cc = tid & 7;
#pragma unroll
    for (int it = 0; it < 2; it++) {
      int sloc = it * 32 + rr;
      bf16x8 v = *(const bf16x8*)(lQ + sloc * 64 + cc * 8);
      *(bf16x8*)(ctx + ((size_t)b * S_ + q0 + sloc) * HID_ + h * HD_ + cc * 8) = v;
    }
  }
}

#define PW(i, j, C) { \
  float* po = out + (size_t)(m0 + wm + (i) * 16 + quad * 4) * 1024 + n0 + wn + (j) * 16 + l16; \
  po[0] = C[0]; po[1024] = C[1]; po[2048] = C[2]; po[3072] = C[3]; }

// ---------------- output projection: out(fp32) = ctx @ Wo^T
__global__ void proj_gemm(
    const bf16* __restrict__ A, const bf16* __restrict__ Wo, float* __restrict__ out) {
  const int m0 = blockIdx.y * 128;
  const int n0 = blockIdx.x * 128;
  __shared__ __align__(16) bf16 lA[128 * 32];
  __shared__ __align__(16) bf16 lB[128 * 32];
  const int tid = threadIdx.x;
  const int lane = tid & 63, w = tid >> 6;
  const int wm = (w >> 1) * 64, wn = (w & 1) * 64;
  const int quad = lane >> 4, l16 = lane & 15;

  DECL_ACC
  const int qa = tid, qb = tid + 256;
  const int ra = qa >> 2, ca = (qa & 3) * 8;
  const int rb = qb >> 2, cb = (qb & 3) * 8;

  for (int k0 = 0; k0 < 1024; k0 += 32) {
    async16(A + (size_t)(m0 + ra) * 1024 + k0 + ca, lA + qa * 8);
    async16(A + (size_t)(m0 + rb) * 1024 + k0 + cb, lA + qb * 8);
    async16(Wo + (size_t)(n0 + ra) * 1024 + k0 + ca, lB + qa * 8);
    async16(Wo + (size_t)(n0 + rb) * 1024 + k0 + cb, lB + qb * 8);
    __syncthreads();
    KLOOP_FRAGS_MFMA
    __syncthreads();
  }
  PW(0, 0, a00) PW(0, 1, a01) PW(0, 2, a02) PW(0, 3, a03)
  PW(1, 0, a10) PW(1, 1, a11) PW(1, 2, a12) PW(1, 3, a13)
  PW(2, 0, a20) PW(2, 1, a21) PW(2, 2, a22) PW(2, 3, a23)
  PW(3, 0, a30) PW(3, 1, a31) PW(3, 2, a32) PW(3, 3, a33)
}

__global__ void sentinel_kernel(float* out, int n, float val) {
  int i = blockIdx.x * 256 + threadIdx.x;
  if (i < n) out[i] = val;
}

extern "C" void kernel_launch(void* const* d_in, const int* in_sizes, int n_in,
                              void* d_out, int out_size, void* d_ws, size_t ws_size,
                              hipStream_t stream) {
  const float* X    = (const float*)d_in[0];
  const float* mask = (const float*)d_in[1];
  const int*   pos  = (const int*)d_in[2];
  const float* Wq   = (const float*)d_in[3];
  const float* Wk   = (const float*)d_in[4];
  const float* Wv   = (const float*)d_in[5];
  const float* Wo   = (const float*)d_in[6];
  float* out = (float*)d_out;

  char* ws = (char*)d_ws;
  const size_t SZ = (size_t)B_ * NH_ * S_ * HD_ * sizeof(bf16);  // 16 MiB
  if (ws_size < 3 * SZ) {
    sentinel_kernel<<<(out_size + 255) / 256, 256, 0, stream>>>(
        out, out_size, (float)(ws_size >> 20));
    return;
  }

  // ws layout (48 MiB): [0,16M) Xb then ctx; [16M,32M) Q; [32M,48M) Vt then Wob.
  bf16* Xb  = (bf16*)(ws);
  bf16* ctx = (bf16*)(ws);
  bf16* Q   = (bf16*)(ws + SZ);
  bf16* Vt  = (bf16*)(ws + 2 * SZ);
  bf16* Wob = (bf16*)(ws + 2 * SZ);
  // d_out hosts bf16 K [0,16M) and Wq/Wk/Wv bf16 [16M,22M) until proj overwrites.
  bf16* Kb  = (bf16*)d_out;
  bf16* Wqb = (bf16*)((char*)d_out + SZ);
  bf16* Wkb = Wqb + 1024 * 1024;
  bf16* Wvb = Wkb + 1024 * 1024;

  const int nX4 = (B_ * S_ * HID_) / 4;
  const int nW4 = (HID_ * HID_) / 4;
  cvt_kernel<<<(nX4 + 255) / 256, 256, 0, stream>>>(X, Xb, nX4);
  cvt_kernel<<<(nW4 + 255) / 256, 256, 0, stream>>>(Wq, Wqb, nW4);
  cvt_kernel<<<(nW4 + 255) / 256, 256, 0, stream>>>(Wk, Wkb, nW4);
  cvt_kernel<<<(nW4 + 255) / 256, 256, 0, stream>>>(Wv, Wvb, nW4);

  qkv_gemm<<<dim3(8, 64, 3), 256, 0, stream>>>(Xb, Wqb, Wkb, Wvb, pos, Q, Kb, Vt);
  attn_kernel<<<dim3(32, 64), 256, 0, stream>>>(Q, Kb, Vt, mask, ctx);

  cvt_kernel<<<(nW4 + 255) / 256, 256, 0, stream>>>(Wo, Wob, nW4);
  proj_gemm<<<dim3(8, 64), 256, 0, stream>>>(ctx, Wob, out);
}